// Round 1
// baseline (403.126 us; speedup 1.0000x reference)
//
#include <hip/hip_runtime.h>

// Problem constants (B=4, N=8192, D=1024, H=16, hd=64, G=512)
#define BB 4
#define NN 8192
#define DD 1024
#define HH 16
#define HD 64
#define GG 512

typedef short short8 __attribute__((ext_vector_type(8)));
typedef float f32x4 __attribute__((ext_vector_type(4)));

__device__ __forceinline__ unsigned short f2bf(float f) {
  union { float f; unsigned int u; } v; v.f = f;
  unsigned int r = v.u + 0x7FFFu + ((v.u >> 16) & 1u);
  return (unsigned short)(r >> 16);
}
__device__ __forceinline__ float bf2f(unsigned short b) {
  union { unsigned int u; float f; } v; v.u = ((unsigned int)b) << 16;
  return v.f;
}

// f32 -> bf16 convert, vectorized float4 / ushort4
__global__ void cvt_kernel(const float* __restrict__ src,
                           unsigned short* __restrict__ dst, int n4) {
  int i = blockIdx.x * blockDim.x + threadIdx.x;
  int stride = gridDim.x * blockDim.x;
  for (int j = i; j < n4; j += stride) {
    float4 f = ((const float4*)src)[j];
    ushort4 u;
    u.x = f2bf(f.x); u.y = f2bf(f.y); u.z = f2bf(f.z); u.w = f2bf(f.w);
    ((ushort4*)dst)[j] = u;
  }
}

// Scatter-free deposit: one wave per (b,h,g) bucket. Positions n mapping to
// bucket g are consecutive; replicate the reference's exact f32 index math.
__global__ __launch_bounds__(256) void deposit_kernel(
    const unsigned short* __restrict__ kv, float* __restrict__ field) {
  int wid = threadIdx.x >> 6;
  int lane = threadIdx.x & 63;
  int tuple = blockIdx.x * 4 + wid;      // (b*16+h)*512 + g
  int g = tuple & (GG - 1);
  int bh = tuple >> 9;                   // b*16+h
  int b = bh >> 4, h = bh & 15;

  int lo = (g * (NN - 1)) / (GG - 1) - 2;
  int hi = ((g + 1) * (NN - 1)) / (GG - 1) + 2;
  if (lo < 0) lo = 0;
  if (hi > NN) hi = NN;

  float acc = 0.0f;
  for (int n = lo; n < hi; ++n) {
    // EXACT replication of reference: trunc((n/8191.f)*511.f)
    float t = ((float)n / 8191.0f) * 511.0f;
    if ((int)t != g) continue;           // wave-uniform branch
    size_t row = ((size_t)(b * NN + n)) * 2048;
    float kd = bf2f(kv[row + h * HD + lane]);
    float s = kd * kd;
    #pragma unroll
    for (int off = 32; off > 0; off >>= 1) s += __shfl_xor(s, off, 64);
    float mag = sqrtf(s);
    float vd = bf2f(kv[row + 1024 + h * HD + lane]);
    acc += vd * mag;
  }
  field[(size_t)tuple * HD + lane] = acc;
}

// Circular conv along G with w_m = exp(-2m)/Z, fconv[g] = sum_m w_m*field[(g+256+m)&511]
// (kernel peak at lag 256; truncated at m=20, e^-40 ~ 4e-18). Output bf16.
__global__ void conv_kernel(const float* __restrict__ field,
                            unsigned short* __restrict__ fconv) {
  int i = blockIdx.x * blockDim.x + threadIdx.x;   // B*H*G*HD = 2M
  int d = i & (HD - 1);
  int g = (i >> 6) & (GG - 1);
  int bh = i >> 15;
  const float* fp = field + (size_t)bh * GG * HD;
  const float invZ = 0.86466471f;                  // 1 / (sum_{m=0}^{256} e^{-2m} + 1e-8)
  float s = 0.0f;
  #pragma unroll
  for (int m = 0; m <= 20; ++m) {
    float w = expf(-2.0f * (float)m) * invZ;
    s += w * fp[(((g + 256 + m) & (GG - 1)) << 6) + d];
  }
  fconv[i] = f2bf(s);
}

// MFMA bf16 GEMM, C[m][n] = sum_k A[m][k]*B[n][k] + bias[n]  (both K-major).
// 128x128 tile, BK=32, 4 waves (2x2), each wave 4x4 fragments of 16x16x32.
// GATHER: A rows come from fconv via (b,n)->g bucket lookup.
// OBF16: write bf16 (for kv), else f32.
template<bool GATHER, bool OBF16>
__global__ __launch_bounds__(256) void gemm_bt(
    const unsigned short* __restrict__ A, const unsigned short* __restrict__ Bm,
    const float* __restrict__ bias, void* __restrict__ Cout,
    int M, int N, int K) {
  __shared__ __align__(16) unsigned short As[128][40];  // +8 pad: conflict-free b128
  __shared__ __align__(16) unsigned short Bs[128][40];

  const int t = threadIdx.x;
  const int bm = blockIdx.y * 128;
  const int bn = blockIdx.x * 128;
  const int wid = t >> 6, lane = t & 63;
  const int wr = (wid >> 1) * 64, wc = (wid & 1) * 64;
  const int l15 = lane & 15, koff = (lane >> 4) * 8;

  f32x4 acc[4][4] = {};

  for (int kk = 0; kk < K; kk += 32) {
    __syncthreads();
    #pragma unroll
    for (int it = 0; it < 2; ++it) {
      int q = t + it * 256;            // 0..511
      int row = q >> 2, seg = (q & 3) * 8;
      uint4 av;
      if constexpr (!GATHER) {
        av = *(const uint4*)(A + (size_t)(bm + row) * K + kk + seg);
      } else {
        int m = bm + row;
        int b = m >> 13, n = m & (NN - 1);
        float tt = ((float)n / 8191.0f) * 511.0f;  // exact ref index math
        int g = (int)tt;
        int c = kk + seg;
        int h = c >> 6, d = c & 63;
        av = *(const uint4*)(A + ((((size_t)b * HH + h) * GG + g) * HD + d));
      }
      *(uint4*)&As[row][seg] = av;
      uint4 bv = *(const uint4*)(Bm + (size_t)(bn + row) * K + kk + seg);
      *(uint4*)&Bs[row][seg] = bv;
    }
    __syncthreads();

    short8 aF[4], bF[4];
    #pragma unroll
    for (int i = 0; i < 4; ++i)
      aF[i] = *(const short8*)&As[wr + i * 16 + l15][koff];
    #pragma unroll
    for (int j = 0; j < 4; ++j)
      bF[j] = *(const short8*)&Bs[wc + j * 16 + l15][koff];
    #pragma unroll
    for (int i = 0; i < 4; ++i)
      #pragma unroll
      for (int j = 0; j < 4; ++j)
        acc[i][j] = __builtin_amdgcn_mfma_f32_16x16x32_bf16(aF[i], bF[j], acc[i][j], 0, 0, 0);
  }

  // Epilogue: C/D layout col=lane&15, row=(lane>>4)*4+reg (m89-verified)
  #pragma unroll
  for (int i = 0; i < 4; ++i) {
    int row0 = bm + wr + i * 16 + (lane >> 4) * 4;
    #pragma unroll
    for (int j = 0; j < 4; ++j) {
      int col = bn + wc + j * 16 + l15;
      float bv = bias[col];
      #pragma unroll
      for (int r = 0; r < 4; ++r) {
        float val = acc[i][j][r] + bv;
        size_t idx = (size_t)(row0 + r) * N + col;
        if constexpr (OBF16) ((unsigned short*)Cout)[idx] = f2bf(val);
        else                 ((float*)Cout)[idx] = val;
      }
    }
  }
}

extern "C" void kernel_launch(void* const* d_in, const int* in_sizes, int n_in,
                              void* d_out, int out_size, void* d_ws, size_t ws_size,
                              hipStream_t stream) {
  const float* x    = (const float*)d_in[0];   // (4,8192,1024)
  const float* Wqkv = (const float*)d_in[1];   // (3072,1024)
  const float* bqkv = (const float*)d_in[2];   // (3072,)
  const float* Wout = (const float*)d_in[3];   // (1024,1024)
  const float* bout = (const float*)d_in[4];   // (1024,)
  float* out = (float*)d_out;                  // (4,8192,1024) f32

  const size_t M = (size_t)BB * NN;            // 32768

  // Workspace layout
  char* ws = (char*)d_ws;
  size_t off = 0;
  unsigned short* xb    = (unsigned short*)(ws + off); off += M * DD * 2;            // 64 MB
  unsigned short* wkvb  = (unsigned short*)(ws + off); off += (size_t)2048 * DD * 2; // 4 MB
  unsigned short* woutb = (unsigned short*)(ws + off); off += (size_t)DD * DD * 2;   // 2 MB
  unsigned short* kv    = (unsigned short*)(ws + off); off += M * 2048 * 2;          // 128 MB
  float*          field = (float*)(ws + off);          off += (size_t)BB*HH*GG*HD*4; // 8 MB
  unsigned short* fconv = (unsigned short*)(ws + off); off += (size_t)BB*HH*GG*HD*2; // 4 MB

  // 1. Convert x, W_kv (rows 1024..3071 of Wqkv), Wout to bf16
  cvt_kernel<<<8192, 256, 0, stream>>>(x, xb, (int)(M * DD / 4));
  cvt_kernel<<<2048, 256, 0, stream>>>(Wqkv + (size_t)DD * DD, wkvb, 2048 * DD / 4);
  cvt_kernel<<<1024, 256, 0, stream>>>(Wout, woutb, DD * DD / 4);

  // 2. kv = x @ Wkv^T + b_kv  -> bf16 (32768 x 2048)
  {
    dim3 grid(2048 / 128, M / 128);
    gemm_bt<false, true><<<grid, 256, 0, stream>>>(xb, wkvb, bqkv + DD, (void*)kv,
                                                   (int)M, 2048, DD);
  }

  // 3. deposit: field[b,h,g,:] = sum_{n in bucket g} v[b,n,h,:] * ||k[b,n,h,:]||
  deposit_kernel<<<BB * HH * GG / 4, 256, 0, stream>>>(kv, field);

  // 4. circular conv along G -> bf16
  conv_kernel<<<BB * HH * GG * HD / 256, 256, 0, stream>>>(field, fconv);

  // 5. out = gather(fconv) @ Wout^T + bout  -> f32 (32768 x 1024)
  {
    dim3 grid(DD / 128, M / 128);
    gemm_bt<true, false><<<grid, 256, 0, stream>>>(fconv, woutb, bout, (void*)out,
                                                   (int)M, DD, DD);
  }
}

// Round 2
// 388.544 us; speedup vs baseline: 1.0375x; 1.0375x over previous
//
#include <hip/hip_runtime.h>

// Problem constants (B=4, N=8192, D=1024, H=16, hd=64, G=512)
#define BB 4
#define NN 8192
#define DD 1024
#define HH 16
#define HD 64
#define GG 512

typedef short short8 __attribute__((ext_vector_type(8)));
typedef float f32x4 __attribute__((ext_vector_type(4)));

__device__ __forceinline__ unsigned short f2bf(float f) {
  union { float f; unsigned int u; } v; v.f = f;
  unsigned int r = v.u + 0x7FFFu + ((v.u >> 16) & 1u);
  return (unsigned short)(r >> 16);
}
__device__ __forceinline__ float bf2f(unsigned short b) {
  union { unsigned int u; float f; } v; v.u = ((unsigned int)b) << 16;
  return v.f;
}

// Async global->LDS 16B copy. LDS dest is wave-uniform base + lane*16 (m104);
// global src is per-lane (m173) -> gather-compatible.
__device__ __forceinline__ void gload16(const void* g, void* l) {
  __builtin_amdgcn_global_load_lds((const __attribute__((address_space(1))) void*)g,
                                   (__attribute__((address_space(3))) void*)l,
                                   16, 0, 0);
}

// f32 -> bf16 convert, vectorized float4 / ushort4
__global__ void cvt_kernel(const float* __restrict__ src,
                           unsigned short* __restrict__ dst, int n4) {
  int i = blockIdx.x * blockDim.x + threadIdx.x;
  int stride = gridDim.x * blockDim.x;
  for (int j = i; j < n4; j += stride) {
    float4 f = ((const float4*)src)[j];
    ushort4 u;
    u.x = f2bf(f.x); u.y = f2bf(f.y); u.z = f2bf(f.z); u.w = f2bf(f.w);
    ((ushort4*)dst)[j] = u;
  }
}

// Scatter-free deposit: one wave per (b,h,g) bucket; exact ref f32 index math.
__global__ __launch_bounds__(256) void deposit_kernel(
    const unsigned short* __restrict__ kv, float* __restrict__ field) {
  int wid = threadIdx.x >> 6;
  int lane = threadIdx.x & 63;
  int tuple = blockIdx.x * 4 + wid;      // (b*16+h)*512 + g
  int g = tuple & (GG - 1);
  int bh = tuple >> 9;                   // b*16+h
  int b = bh >> 4, h = bh & 15;

  int lo = (g * (NN - 1)) / (GG - 1) - 2;
  int hi = ((g + 1) * (NN - 1)) / (GG - 1) + 2;
  if (lo < 0) lo = 0;
  if (hi > NN) hi = NN;

  float acc = 0.0f;
  for (int n = lo; n < hi; ++n) {
    float t = ((float)n / 8191.0f) * 511.0f;   // EXACT ref: trunc((n/8191)*511)
    if ((int)t != g) continue;                 // wave-uniform branch
    size_t row = ((size_t)(b * NN + n)) * 2048;
    float kd = bf2f(kv[row + h * HD + lane]);
    float s = kd * kd;
    #pragma unroll
    for (int off = 32; off > 0; off >>= 1) s += __shfl_xor(s, off, 64);
    float mag = sqrtf(s);
    float vd = bf2f(kv[row + 1024 + h * HD + lane]);
    acc += vd * mag;
  }
  field[(size_t)tuple * HD + lane] = acc;
}

// Circular conv along G: fconv[g] = sum_m w_m * field[(g+256+m)&511],
// w_m = exp(-2m)/Z, truncated at m=20 (e^-40). Output bf16.
__global__ void conv_kernel(const float* __restrict__ field,
                            unsigned short* __restrict__ fconv) {
  int i = blockIdx.x * blockDim.x + threadIdx.x;   // B*H*G*HD = 2M
  int d = i & (HD - 1);
  int g = (i >> 6) & (GG - 1);
  int bh = i >> 15;
  const float* fp = field + (size_t)bh * GG * HD;
  const float invZ = 0.86466471f;                  // 1/(sum e^{-2m} + 1e-8)
  float s = 0.0f;
  #pragma unroll
  for (int m = 0; m <= 20; ++m) {
    float w = expf(-2.0f * (float)m) * invZ;
    s += w * fp[(((g + 256 + m) & (GG - 1)) << 6) + d];
  }
  fconv[i] = f2bf(s);
}

// MFMA bf16 GEMM (m97 structure): 128x128 tile, BK=32, 4 waves (2x2),
// global_load_lds width-16 staging into linear [128][32] LDS, 2 barriers/K-step.
// C[m][n] = sum_k A[m][k]*B[n][k] + bias[n]  (both K-major).
// GATHER: A rows come from fconv via the (b,n)->g bucket lookup.
template<bool GATHER, bool OBF16>
__global__ __launch_bounds__(256) void gemm_bt(
    const unsigned short* __restrict__ A, const unsigned short* __restrict__ Bm,
    const float* __restrict__ bias, void* __restrict__ Cout,
    int M, int N, int K) {
  __shared__ __align__(16) unsigned short As[128 * 32];   // 8 KB, linear (gload_lds dest)
  __shared__ __align__(16) unsigned short Bs[128 * 32];   // 8 KB

  const int t = threadIdx.x;
  const int bm = blockIdx.y * 128;
  const int bn = blockIdx.x * 128;
  const int wid = t >> 6, lane = t & 63;
  const int wr = (wid >> 1) * 64, wc = (wid & 1) * 64;
  const int l15 = lane & 15, koff = (lane >> 4) * 8;

  // Staging: wave covers 16 rows per gload16 instr (64 lanes x 16B = 1024B).
  // Lane i -> row base + i/4, short-offset (i&3)*8. Global addr mirrors this.
  const int srow = lane >> 2;          // 0..15
  const int sseg = (lane & 3) * 8;     // 0,8,16,24

  f32x4 acc[4][4] = {};

  for (int kk = 0; kk < K; kk += 32) {
    #pragma unroll
    for (int it = 0; it < 2; ++it) {
      const int rbase = wid * 16 + it * 64;      // wave-uniform LDS slab
      const int row = rbase + srow;
      const unsigned short* ga;
      if constexpr (!GATHER) {
        ga = A + (size_t)(bm + row) * K + kk + sseg;
      } else {
        int m = bm + row;
        int b = m >> 13, n = m & (NN - 1);
        float tt = ((float)n / 8191.0f) * 511.0f;  // exact ref index math
        int g = (int)tt;
        int c = kk + sseg;
        ga = A + ((((size_t)b * HH + (c >> 6)) * GG + g) * HD + (c & 63));
      }
      gload16(ga, &As[rbase * 32]);
      gload16(Bm + (size_t)(bn + row) * K + kk + sseg, &Bs[rbase * 32]);
    }
    __syncthreads();   // vmcnt(0) drain + barrier: tiles ready

    short8 aF[4], bF[4];
    #pragma unroll
    for (int i = 0; i < 4; ++i)
      aF[i] = *(const short8*)&As[(wr + i * 16 + l15) * 32 + koff];
    #pragma unroll
    for (int j = 0; j < 4; ++j)
      bF[j] = *(const short8*)&Bs[(wc + j * 16 + l15) * 32 + koff];
    #pragma unroll
    for (int i = 0; i < 4; ++i)
      #pragma unroll
      for (int j = 0; j < 4; ++j)
        acc[i][j] = __builtin_amdgcn_mfma_f32_16x16x32_bf16(aF[i], bF[j], acc[i][j], 0, 0, 0);
    __syncthreads();   // LDS reads done before next stage overwrites
  }

  // Epilogue: C/D layout col=lane&15, row=(lane>>4)*4+reg (m89-verified)
  #pragma unroll
  for (int i = 0; i < 4; ++i) {
    int row0 = bm + wr + i * 16 + (lane >> 4) * 4;
    #pragma unroll
    for (int j = 0; j < 4; ++j) {
      int col = bn + wc + j * 16 + l15;
      float bv = bias[col];
      #pragma unroll
      for (int r = 0; r < 4; ++r) {
        float val = acc[i][j][r] + bv;
        size_t idx = (size_t)(row0 + r) * N + col;
        if constexpr (OBF16) ((unsigned short*)Cout)[idx] = f2bf(val);
        else                 ((float*)Cout)[idx] = val;
      }
    }
  }
}

extern "C" void kernel_launch(void* const* d_in, const int* in_sizes, int n_in,
                              void* d_out, int out_size, void* d_ws, size_t ws_size,
                              hipStream_t stream) {
  const float* x    = (const float*)d_in[0];   // (4,8192,1024)
  const float* Wqkv = (const float*)d_in[1];   // (3072,1024)
  const float* bqkv = (const float*)d_in[2];   // (3072,)
  const float* Wout = (const float*)d_in[3];   // (1024,1024)
  const float* bout = (const float*)d_in[4];   // (1024,)
  float* out = (float*)d_out;                  // (4,8192,1024) f32

  const size_t M = (size_t)BB * NN;            // 32768

  // Workspace layout
  char* ws = (char*)d_ws;
  size_t off = 0;
  unsigned short* xb    = (unsigned short*)(ws + off); off += M * DD * 2;            // 64 MB
  unsigned short* wkvb  = (unsigned short*)(ws + off); off += (size_t)2048 * DD * 2; // 4 MB
  unsigned short* woutb = (unsigned short*)(ws + off); off += (size_t)DD * DD * 2;   // 2 MB
  unsigned short* kv    = (unsigned short*)(ws + off); off += M * 2048 * 2;          // 128 MB
  float*          field = (float*)(ws + off);          off += (size_t)BB*HH*GG*HD*4; // 8 MB
  unsigned short* fconv = (unsigned short*)(ws + off); off += (size_t)BB*HH*GG*HD*2; // 4 MB

  // 1. Convert x, W_kv (rows 1024..3071 of Wqkv), Wout to bf16
  cvt_kernel<<<8192, 256, 0, stream>>>(x, xb, (int)(M * DD / 4));
  cvt_kernel<<<2048, 256, 0, stream>>>(Wqkv + (size_t)DD * DD, wkvb, 2048 * DD / 4);
  cvt_kernel<<<1024, 256, 0, stream>>>(Wout, woutb, DD * DD / 4);

  // 2. kv = x @ Wkv^T + b_kv  -> bf16 (32768 x 2048)
  {
    dim3 grid(2048 / 128, M / 128);
    gemm_bt<false, true><<<grid, 256, 0, stream>>>(xb, wkvb, bqkv + DD, (void*)kv,
                                                   (int)M, 2048, DD);
  }

  // 3. deposit: field[b,h,g,:] = sum_{n in bucket g} v[b,n,h,:] * ||k[b,n,h,:]||
  deposit_kernel<<<BB * HH * GG / 4, 256, 0, stream>>>(kv, field);

  // 4. circular conv along G -> bf16
  conv_kernel<<<BB * HH * GG * HD / 256, 256, 0, stream>>>(field, fconv);

  // 5. out = gather(fconv) @ Wout^T + bout  -> f32 (32768 x 1024)
  {
    dim3 grid(DD / 128, M / 128);
    gemm_bt<true, false><<<grid, 256, 0, stream>>>(fconv, woutb, bout, (void*)out,
                                                   (int)M, DD, DD);
  }
}

// Round 3
// 336.492 us; speedup vs baseline: 1.1980x; 1.1547x over previous
//
#include <hip/hip_runtime.h>

// Problem constants (B=4, N=8192, D=1024, H=16, hd=64, G=512)
#define BB 4
#define NN 8192
#define DD 1024
#define HH 16
#define HD 64
#define GG 512

typedef short short8 __attribute__((ext_vector_type(8)));
typedef float f32x4 __attribute__((ext_vector_type(4)));

__device__ __forceinline__ unsigned short f2bf(float f) {
  union { float f; unsigned int u; } v; v.f = f;
  unsigned int r = v.u + 0x7FFFu + ((v.u >> 16) & 1u);
  return (unsigned short)(r >> 16);
}
__device__ __forceinline__ float bf2f(unsigned short b) {
  union { unsigned int u; float f; } v; v.u = ((unsigned int)b) << 16;
  return v.f;
}

// Async global->LDS 16B copy: LDS dest = wave-uniform base + lane*16 (m104);
// global src is per-lane (m173).
__device__ __forceinline__ void gload16(const void* g, void* l) {
  __builtin_amdgcn_global_load_lds((const __attribute__((address_space(1))) void*)g,
                                   (__attribute__((address_space(3))) void*)l,
                                   16, 0, 0);
}

// f32 -> bf16 convert, vectorized
__global__ void cvt_kernel(const float* __restrict__ src,
                           unsigned short* __restrict__ dst, int n4) {
  int i = blockIdx.x * blockDim.x + threadIdx.x;
  int stride = gridDim.x * blockDim.x;
  for (int j = i; j < n4; j += stride) {
    float4 f = ((const float4*)src)[j];
    ushort4 u;
    u.x = f2bf(f.x); u.y = f2bf(f.y); u.z = f2bf(f.z); u.w = f2bf(f.w);
    ((ushort4*)dst)[j] = u;
  }
}

// Scatter-free deposit: one wave per (b,h,g) bucket; exact ref f32 index math.
__global__ __launch_bounds__(256) void deposit_kernel(
    const unsigned short* __restrict__ kv, float* __restrict__ field) {
  int wid = threadIdx.x >> 6;
  int lane = threadIdx.x & 63;
  int tuple = blockIdx.x * 4 + wid;      // (b*16+h)*512 + g
  int g = tuple & (GG - 1);
  int bh = tuple >> 9;
  int b = bh >> 4, h = bh & 15;

  int lo = (g * (NN - 1)) / (GG - 1) - 2;
  int hi = ((g + 1) * (NN - 1)) / (GG - 1) + 2;
  if (lo < 0) lo = 0;
  if (hi > NN) hi = NN;

  float acc = 0.0f;
  for (int n = lo; n < hi; ++n) {
    float t = ((float)n / 8191.0f) * 511.0f;   // EXACT ref: trunc((n/8191)*511)
    if ((int)t != g) continue;
    size_t row = ((size_t)(b * NN + n)) * 2048;
    float kd = bf2f(kv[row + h * HD + lane]);
    float s = kd * kd;
    #pragma unroll
    for (int off = 32; off > 0; off >>= 1) s += __shfl_xor(s, off, 64);
    float mag = sqrtf(s);
    float vd = bf2f(kv[row + 1024 + h * HD + lane]);
    acc += vd * mag;
  }
  field[(size_t)tuple * HD + lane] = acc;
}

// Circular conv along G: fconv[g] = sum_m w_m * field[(g+256+m)&511],
// w_m = exp(-2m)/Z, truncated at m=20. Output bf16.
__global__ void conv_kernel(const float* __restrict__ field,
                            unsigned short* __restrict__ fconv) {
  int i = blockIdx.x * blockDim.x + threadIdx.x;   // B*H*G*HD = 2M
  int d = i & (HD - 1);
  int g = (i >> 6) & (GG - 1);
  int bh = i >> 15;
  const float* fp = field + (size_t)bh * GG * HD;
  const float invZ = 0.86466471f;
  float s = 0.0f;
  #pragma unroll
  for (int m = 0; m <= 20; ++m) {
    float w = expf(-2.0f * (float)m) * invZ;
    s += w * fp[(((g + 256 + m) & (GG - 1)) << 6) + d];
  }
  fconv[i] = f2bf(s);
}

// ===================== 256x256 ring-pipelined MFMA GEMM =====================
// C[m][n] = sum_k A[m][k]*B[n][k] + bias[n], both operands K-major, K=32*nt.
// 8 waves (2M x 4N), 512 threads, per-wave output 128x64 (acc[8][4] of 16x16).
// LDS: ring of 4 K-tile buffers (A 256x32 + B 256x32 bf16 = 32 KB each).
// Pipeline: stage tile t+3 -> vmcnt(12) [tile t landed, 3 in flight] ->
// barrier -> 12x ds_read_b128 (XOR-swizzled, conflict-free) -> lgkmcnt(0) ->
// 32 MFMA (setprio) -> barrier.  Counted vmcnt = T4; never drains prefetch.
template<bool GATHER, bool OBF16>
__global__ __launch_bounds__(512, 2) void gemm_bt(
    const unsigned short* __restrict__ A, const unsigned short* __restrict__ Bm,
    const float* __restrict__ bias, void* __restrict__ Cout,
    int M, int N, int K) {
  __shared__ __align__(16) unsigned short smem[4 * 16384];  // 128 KB

  const int t512 = threadIdx.x;
  const int wv = t512 >> 6, lane = t512 & 63;
  const int wm = wv >> 2, wn = wv & 3;
  const int l15 = lane & 15, sr = lane >> 4;
  const int nt = K >> 5;

  // --- XCD-aware bijective block swizzle (grid.x divisible by 8) ---
  const int nwg = gridDim.x;
  const int lin = blockIdx.x;
  const int swz = (lin & 7) * (nwg >> 3) + (lin >> 3);
  const int gx = N >> 8;                    // N/256 col-blocks
  const int bm = (swz / gx) * 256;
  const int bn = (swz % gx) * 256;

  // --- staging geometry: 4 gload16/thread/tile (A half0, A half1, B h0, B h1)
  // load L covers rows L*128 + wv*16 + lane/4; physical 16B slot = lane&3.
  // Swizzle: slot p of row r holds global k-segment p ^ ((r>>1)&3).
  const int srow0 = wv * 16 + (lane >> 2);       // row for L=0 (L=1: +128)
  const int sg = (lane & 3) ^ ((srow0 >> 1) & 3);  // same for L=0/1 (+128 keeps (r>>1)&3)
  const int aL0 = wv * 1024;                     // byte LDS offset, wave-uniform
  const int aL1 = 8192 + wv * 1024;

  const unsigned short* aG0;
  const unsigned short* aG1;
  size_t pb0 = 0, pb1 = 0;                       // gather bases
  if constexpr (!GATHER) {
    aG0 = A + (size_t)(bm + srow0) * K + sg * 8;
    aG1 = A + (size_t)(bm + srow0 + 128) * K + sg * 8;
  } else {
    int m0 = bm + srow0, m1 = m0 + 128;
    int b0 = m0 >> 13, n0 = m0 & (NN - 1);
    int b1 = m1 >> 13, n1 = m1 & (NN - 1);
    int g0 = (int)(((float)n0 / 8191.0f) * 511.0f);   // exact ref index math
    int g1 = (int)(((float)n1 / 8191.0f) * 511.0f);
    pb0 = (size_t)b0 * 524288 + (size_t)g0 * 64;
    pb1 = (size_t)b1 * 524288 + (size_t)g1 * 64;
    aG0 = A; aG1 = A;
  }
  const unsigned short* bG0 = Bm + (size_t)(bn + srow0) * K + sg * 8;
  const unsigned short* bG1 = Bm + (size_t)(bn + srow0 + 128) * K + sg * 8;

  auto stage = [&](int t, int q) {
    char* base = (char*)smem + q * 32768;
    if constexpr (!GATHER) {
      gload16(aG0 + (size_t)t * 32, base + aL0);
      gload16(aG1 + (size_t)t * 32, base + aL1);
    } else {
      int c = t * 32 + sg * 8;
      size_t ho = (size_t)(c >> 6) * 32768 + (c & 63);
      gload16(A + pb0 + ho, base + aL0);
      gload16(A + pb1 + ho, base + aL1);
    }
    gload16(bG0 + (size_t)t * 32, base + 16384 + aL0);
    gload16(bG1 + (size_t)t * 32, base + 16384 + aL1);
  };

  // --- fragment LDS byte offsets (swizzled), buf-relative ---
  int aOffB[8], bOffB[4];
  #pragma unroll
  for (int i = 0; i < 8; ++i) {
    int r = wm * 128 + i * 16 + l15;
    aOffB[i] = r * 64 + ((sr ^ ((r >> 1) & 3)) * 16);
  }
  #pragma unroll
  for (int j = 0; j < 4; ++j) {
    int r = wn * 64 + j * 16 + l15;
    bOffB[j] = r * 64 + ((sr ^ ((r >> 1) & 3)) * 16);
  }

  f32x4 acc[8][4] = {};

  auto compute = [&](int q) {
    const char* base = (const char*)smem + q * 32768;
    short8 aF[8], bF[4];
    #pragma unroll
    for (int i = 0; i < 8; ++i) aF[i] = *(const short8*)(base + aOffB[i]);
    #pragma unroll
    for (int j = 0; j < 4; ++j) bF[j] = *(const short8*)(base + 16384 + bOffB[j]);
    asm volatile("s_waitcnt lgkmcnt(0)" ::: "memory");
    __builtin_amdgcn_sched_barrier(0);            // rule #18: keep MFMA below
    __builtin_amdgcn_s_setprio(1);
    #pragma unroll
    for (int i = 0; i < 8; ++i)
      #pragma unroll
      for (int j = 0; j < 4; ++j)
        acc[i][j] = __builtin_amdgcn_mfma_f32_16x16x32_bf16(aF[i], bF[j], acc[i][j], 0, 0, 0);
    __builtin_amdgcn_s_setprio(0);
  };

  // --- prologue: 3 tiles in flight ---
  stage(0, 0); stage(1, 1); stage(2, 2);

  for (int t = 0; t < nt; ++t) {
    if (t + 3 < nt) stage(t + 3, (t + 3) & 3);
    int rem = nt - 1 - t;                     // tiles younger than t in flight
    if (rem >= 3)      asm volatile("s_waitcnt vmcnt(12)" ::: "memory");
    else if (rem == 2) asm volatile("s_waitcnt vmcnt(8)" ::: "memory");
    else if (rem == 1) asm volatile("s_waitcnt vmcnt(4)" ::: "memory");
    else               asm volatile("s_waitcnt vmcnt(0)" ::: "memory");
    __builtin_amdgcn_s_barrier();             // tile t visible to all waves
    compute(t & 3);
    asm volatile("" ::: "memory");
    __builtin_amdgcn_s_barrier();             // reads of buf t&3 done (lgkmcnt(0) above)
  }

  // --- epilogue: C/D layout col=lane&15, row=(lane>>4)*4+reg (m89-verified)
  #pragma unroll
  for (int i = 0; i < 8; ++i) {
    int row0 = bm + wm * 128 + i * 16 + (lane >> 4) * 4;
    #pragma unroll
    for (int j = 0; j < 4; ++j) {
      int col = bn + wn * 64 + j * 16 + l15;
      float bv = bias[col];
      #pragma unroll
      for (int r = 0; r < 4; ++r) {
        float val = acc[i][j][r] + bv;
        size_t idx = (size_t)(row0 + r) * N + col;
        if constexpr (OBF16) ((unsigned short*)Cout)[idx] = f2bf(val);
        else                 ((float*)Cout)[idx] = val;
      }
    }
  }
}

extern "C" void kernel_launch(void* const* d_in, const int* in_sizes, int n_in,
                              void* d_out, int out_size, void* d_ws, size_t ws_size,
                              hipStream_t stream) {
  const float* x    = (const float*)d_in[0];   // (4,8192,1024)
  const float* Wqkv = (const float*)d_in[1];   // (3072,1024)
  const float* bqkv = (const float*)d_in[2];   // (3072,)
  const float* Wout = (const float*)d_in[3];   // (1024,1024)
  const float* bout = (const float*)d_in[4];   // (1024,)
  float* out = (float*)d_out;                  // (4,8192,1024) f32

  const size_t M = (size_t)BB * NN;            // 32768

  // Workspace layout
  char* ws = (char*)d_ws;
  size_t off = 0;
  unsigned short* xb    = (unsigned short*)(ws + off); off += M * DD * 2;            // 64 MB
  unsigned short* wkvb  = (unsigned short*)(ws + off); off += (size_t)2048 * DD * 2; // 4 MB
  unsigned short* woutb = (unsigned short*)(ws + off); off += (size_t)DD * DD * 2;   // 2 MB
  unsigned short* kv    = (unsigned short*)(ws + off); off += M * 2048 * 2;          // 128 MB
  float*          field = (float*)(ws + off);          off += (size_t)BB*HH*GG*HD*4; // 8 MB
  unsigned short* fconv = (unsigned short*)(ws + off); off += (size_t)BB*HH*GG*HD*2; // 4 MB

  // 1. Convert x, W_kv (rows 1024..3071 of Wqkv), Wout to bf16
  cvt_kernel<<<8192, 256, 0, stream>>>(x, xb, (int)(M * DD / 4));
  cvt_kernel<<<2048, 256, 0, stream>>>(Wqkv + (size_t)DD * DD, wkvb, 2048 * DD / 4);
  cvt_kernel<<<1024, 256, 0, stream>>>(Wout, woutb, DD * DD / 4);

  // 2. kv = x @ Wkv^T + b_kv  -> bf16 (32768 x 2048): grid 8x128 = 1024 blocks
  gemm_bt<false, true><<<(2048 / 256) * (M / 256), 512, 0, stream>>>(
      xb, wkvb, bqkv + DD, (void*)kv, (int)M, 2048, DD);

  // 3. deposit
  deposit_kernel<<<BB * HH * GG / 4, 256, 0, stream>>>(kv, field);

  // 4. circular conv -> bf16
  conv_kernel<<<BB * HH * GG * HD / 256, 256, 0, stream>>>(field, fconv);

  // 5. out = gather(fconv) @ Wout^T + bout  -> f32: grid 4x128 = 512 blocks
  gemm_bt<true, false><<<(DD / 256) * (M / 256), 512, 0, stream>>>(
      fconv, woutb, bout, (void*)out, (int)M, DD, DD);
}

// Round 4
// 334.932 us; speedup vs baseline: 1.2036x; 1.0047x over previous
//
#include <hip/hip_runtime.h>

// Problem constants (B=4, N=8192, D=1024, H=16, hd=64, G=512)
#define BB 4
#define NN 8192
#define DD 1024
#define HH 16
#define HD 64
#define GG 512

typedef short short8 __attribute__((ext_vector_type(8)));
typedef float f32x4 __attribute__((ext_vector_type(4)));

__device__ __forceinline__ unsigned short f2bf(float f) {
  union { float f; unsigned int u; } v; v.f = f;
  unsigned int r = v.u + 0x7FFFu + ((v.u >> 16) & 1u);
  return (unsigned short)(r >> 16);
}
__device__ __forceinline__ float bf2f(unsigned short b) {
  union { unsigned int u; float f; } v; v.u = ((unsigned int)b) << 16;
  return v.f;
}

// Async global->LDS 16B copy: LDS dest = wave-uniform base + lane*16 (m104);
// global src is per-lane (m173).
__device__ __forceinline__ void gload16(const void* g, void* l) {
  __builtin_amdgcn_global_load_lds((const __attribute__((address_space(1))) void*)g,
                                   (__attribute__((address_space(3))) void*)l,
                                   16, 0, 0);
}

// f32 -> bf16 convert, vectorized
__global__ void cvt_kernel(const float* __restrict__ src,
                           unsigned short* __restrict__ dst, int n4) {
  int i = blockIdx.x * blockDim.x + threadIdx.x;
  int stride = gridDim.x * blockDim.x;
  for (int j = i; j < n4; j += stride) {
    float4 f = ((const float4*)src)[j];
    ushort4 u;
    u.x = f2bf(f.x); u.y = f2bf(f.y); u.z = f2bf(f.z); u.w = f2bf(f.w);
    ((ushort4*)dst)[j] = u;
  }
}

// Scatter-free deposit: one wave per (b,h,g) bucket; exact ref f32 index math.
__global__ __launch_bounds__(256) void deposit_kernel(
    const unsigned short* __restrict__ kv, float* __restrict__ field) {
  int wid = threadIdx.x >> 6;
  int lane = threadIdx.x & 63;
  int tuple = blockIdx.x * 4 + wid;      // (b*16+h)*512 + g
  int g = tuple & (GG - 1);
  int bh = tuple >> 9;
  int b = bh >> 4, h = bh & 15;

  int lo = (g * (NN - 1)) / (GG - 1) - 2;
  int hi = ((g + 1) * (NN - 1)) / (GG - 1) + 2;
  if (lo < 0) lo = 0;
  if (hi > NN) hi = NN;

  float acc = 0.0f;
  for (int n = lo; n < hi; ++n) {
    float t = ((float)n / 8191.0f) * 511.0f;   // EXACT ref: trunc((n/8191)*511)
    if ((int)t != g) continue;
    size_t row = ((size_t)(b * NN + n)) * 2048;
    float kd = bf2f(kv[row + h * HD + lane]);
    float s = kd * kd;
    #pragma unroll
    for (int off = 32; off > 0; off >>= 1) s += __shfl_xor(s, off, 64);
    float mag = sqrtf(s);
    float vd = bf2f(kv[row + 1024 + h * HD + lane]);
    acc += vd * mag;
  }
  field[(size_t)tuple * HD + lane] = acc;
}

// Circular conv along G: fconv[g] = sum_m w_m * field[(g+256+m)&511],
// w_m = exp(-2m)/Z, truncated at m=20. Output bf16.
__global__ void conv_kernel(const float* __restrict__ field,
                            unsigned short* __restrict__ fconv) {
  int i = blockIdx.x * blockDim.x + threadIdx.x;   // B*H*G*HD = 2M
  int d = i & (HD - 1);
  int g = (i >> 6) & (GG - 1);
  int bh = i >> 15;
  const float* fp = field + (size_t)bh * GG * HD;
  const float invZ = 0.86466471f;
  float s = 0.0f;
  #pragma unroll
  for (int m = 0; m <= 20; ++m) {
    float w = expf(-2.0f * (float)m) * invZ;
    s += w * fp[(((g + 256 + m) & (GG - 1)) << 6) + d];
  }
  fconv[i] = f2bf(s);
}

// ============ 256x256 ring-pipelined MFMA GEMM, 2-phase interleave ==========
// C[m][n] = sum_k A[m][k]*B[n][k] + bias[n], K-major operands, K=32*nt.
// 8 waves (2M x 4N), per-wave output 128x64 (acc[8][4] of 16x16x32).
// LDS: ring of 4 K-tile buffers (A 256x32 + B 256x32 = 32 KB each), XOR-swizzle
// slot = sr ^ ((row>>1)&3) -> 0 bank conflicts (verified R3).
// Per K-tile, 2 phases (m201 pattern): {issue ds_reads + stage -> barrier ->
// lgkmcnt(0) -> 16 MFMA (setprio) -> barrier}. LDS reads drain during the
// barrier/other waves' MFMA window instead of stalling the wave.
// Counted vmcnt(8) once per K-tile (never 0 in steady state).
template<bool GATHER, bool OBF16>
__global__ __launch_bounds__(512, 2) void gemm_bt(
    const unsigned short* __restrict__ A, const unsigned short* __restrict__ Bm,
    const float* __restrict__ bias, void* __restrict__ Cout,
    int M, int N, int K) {
  __shared__ __align__(16) unsigned short smem[4 * 16384];  // 128 KB

  const int t512 = threadIdx.x;
  const int wv = t512 >> 6, lane = t512 & 63;
  const int wm = wv >> 2, wn = wv & 3;
  const int l15 = lane & 15, sr = lane >> 4;
  const int nt = K >> 5;

  // --- XCD-aware bijective block swizzle (grid.x divisible by 8) ---
  const int nwg = gridDim.x;
  const int lin = blockIdx.x;
  const int swz = (lin & 7) * (nwg >> 3) + (lin >> 3);
  const int gx = N >> 8;                    // N/256 col-blocks
  const int bm = (swz / gx) * 256;
  const int bn = (swz % gx) * 256;

  // --- staging geometry: 4 gload16/thread/tile (A h0, A h1, B h0, B h1)
  // wave wv covers rows wv*16 + lane/4 (+128 for half1), 16B slot lane&3.
  // Swizzle: physical slot p of row r holds k-segment p ^ ((r>>1)&3).
  const int srow0 = wv * 16 + (lane >> 2);
  const int sg = (lane & 3) ^ ((srow0 >> 1) & 3);
  const int aL0 = wv * 1024;                     // byte LDS offsets (wave-uniform)
  const int aL1 = 8192 + wv * 1024;

  const unsigned short* aG0;
  const unsigned short* aG1;
  size_t pb0 = 0, pb1 = 0;
  if constexpr (!GATHER) {
    aG0 = A + (size_t)(bm + srow0) * K + sg * 8;
    aG1 = A + (size_t)(bm + srow0 + 128) * K + sg * 8;
  } else {
    int m0 = bm + srow0, m1 = m0 + 128;
    int b0 = m0 >> 13, n0 = m0 & (NN - 1);
    int b1 = m1 >> 13, n1 = m1 & (NN - 1);
    int g0 = (int)(((float)n0 / 8191.0f) * 511.0f);   // exact ref index math
    int g1 = (int)(((float)n1 / 8191.0f) * 511.0f);
    pb0 = (size_t)b0 * 524288 + (size_t)g0 * 64;
    pb1 = (size_t)b1 * 524288 + (size_t)g1 * 64;
    aG0 = A; aG1 = A;
  }
  const unsigned short* bG0 = Bm + (size_t)(bn + srow0) * K + sg * 8;
  const unsigned short* bG1 = Bm + (size_t)(bn + srow0 + 128) * K + sg * 8;

  auto stageA = [&](int t, int q) {
    char* base = (char*)smem + q * 32768;
    if constexpr (!GATHER) {
      gload16(aG0 + (size_t)t * 32, base + aL0);
      gload16(aG1 + (size_t)t * 32, base + aL1);
    } else {
      int c = t * 32 + sg * 8;
      size_t ho = (size_t)(c >> 6) * 32768 + (c & 63);
      gload16(A + pb0 + ho, base + aL0);
      gload16(A + pb1 + ho, base + aL1);
    }
  };
  auto stageB = [&](int t, int q) {
    char* base = (char*)smem + q * 32768;
    gload16(bG0 + (size_t)t * 32, base + 16384 + aL0);
    gload16(bG1 + (size_t)t * 32, base + 16384 + aL1);
  };

  // --- fragment LDS byte offsets (swizzled), buf-relative ---
  int aOffB[8], bOffB[4];
  #pragma unroll
  for (int i = 0; i < 8; ++i) {
    int r = wm * 128 + i * 16 + l15;
    aOffB[i] = r * 64 + ((sr ^ ((r >> 1) & 3)) * 16);
  }
  #pragma unroll
  for (int j = 0; j < 4; ++j) {
    int r = wn * 64 + j * 16 + l15;
    bOffB[j] = r * 64 + ((sr ^ ((r >> 1) & 3)) * 16);
  }

  f32x4 acc[8][4] = {};

  // --- prologue: 3 tiles in flight; wait tile 0 (4 oldest) before compute ---
  stageA(0, 0); stageB(0, 0);
  stageA(1, 1); stageB(1, 1);
  stageA(2, 2); stageB(2, 2);
  asm volatile("s_waitcnt vmcnt(8)" ::: "memory");
  __builtin_amdgcn_s_barrier();

  for (int t = 0; t < nt; ++t) {
    const char* base = (const char*)smem + (t & 3) * 32768;
    short8 aF[8], bF[4];

    // ---- phase 1: issue reads + A-stage, barrier, wait, MFMA quadrant i<4 ----
    if (t + 3 < nt) stageA(t + 3, (t + 3) & 3);
    #pragma unroll
    for (int i = 0; i < 4; ++i) aF[i] = *(const short8*)(base + aOffB[i]);
    #pragma unroll
    for (int j = 0; j < 4; ++j) bF[j] = *(const short8*)(base + 16384 + bOffB[j]);
    __builtin_amdgcn_s_barrier();
    asm volatile("s_waitcnt lgkmcnt(0)" ::: "memory");
    __builtin_amdgcn_sched_barrier(0);            // rule #18
    __builtin_amdgcn_s_setprio(1);
    #pragma unroll
    for (int i = 0; i < 4; ++i)
      #pragma unroll
      for (int j = 0; j < 4; ++j)
        acc[i][j] = __builtin_amdgcn_mfma_f32_16x16x32_bf16(aF[i], bF[j], acc[i][j], 0, 0, 0);
    __builtin_amdgcn_s_setprio(0);
    __builtin_amdgcn_s_barrier();

    // ---- phase 2: issue reads + B-stage, counted vmcnt, barrier, MFMA i>=4 ----
    if (t + 3 < nt) stageB(t + 3, (t + 3) & 3);
    #pragma unroll
    for (int i = 4; i < 8; ++i) aF[i] = *(const short8*)(base + aOffB[i]);
    {
      int rem = nt - 1 - t;                 // tiles staged beyond t
      if (rem >= 3)      asm volatile("s_waitcnt vmcnt(8)" ::: "memory");
      else if (rem == 2) asm volatile("s_waitcnt vmcnt(4)" ::: "memory");
      else               asm volatile("s_waitcnt vmcnt(0)" ::: "memory");
    }
    __builtin_amdgcn_s_barrier();           // tile t+1 visible to all waves
    asm volatile("s_waitcnt lgkmcnt(0)" ::: "memory");
    __builtin_amdgcn_sched_barrier(0);
    __builtin_amdgcn_s_setprio(1);
    #pragma unroll
    for (int i = 4; i < 8; ++i)
      #pragma unroll
      for (int j = 0; j < 4; ++j)
        acc[i][j] = __builtin_amdgcn_mfma_f32_16x16x32_bf16(aF[i], bF[j], acc[i][j], 0, 0, 0);
    __builtin_amdgcn_s_setprio(0);
    __builtin_amdgcn_s_barrier();           // reads of this buf done -> reusable
  }

  // --- epilogue: C/D layout col=lane&15, row=(lane>>4)*4+reg (m89-verified)
  #pragma unroll
  for (int i = 0; i < 8; ++i) {
    int row0 = bm + wm * 128 + i * 16 + (lane >> 4) * 4;
    #pragma unroll
    for (int j = 0; j < 4; ++j) {
      int col = bn + wn * 64 + j * 16 + l15;
      float bv = bias[col];
      #pragma unroll
      for (int r = 0; r < 4; ++r) {
        float val = acc[i][j][r] + bv;
        size_t idx = (size_t)(row0 + r) * N + col;
        if constexpr (OBF16) ((unsigned short*)Cout)[idx] = f2bf(val);
        else                 ((float*)Cout)[idx] = val;
      }
    }
  }
}

extern "C" void kernel_launch(void* const* d_in, const int* in_sizes, int n_in,
                              void* d_out, int out_size, void* d_ws, size_t ws_size,
                              hipStream_t stream) {
  const float* x    = (const float*)d_in[0];   // (4,8192,1024)
  const float* Wqkv = (const float*)d_in[1];   // (3072,1024)
  const float* bqkv = (const float*)d_in[2];   // (3072,)
  const float* Wout = (const float*)d_in[3];   // (1024,1024)
  const float* bout = (const float*)d_in[4];   // (1024,)
  float* out = (float*)d_out;                  // (4,8192,1024) f32

  const size_t M = (size_t)BB * NN;            // 32768

  // Workspace layout
  char* ws = (char*)d_ws;
  size_t off = 0;
  unsigned short* xb    = (unsigned short*)(ws + off); off += M * DD * 2;            // 64 MB
  unsigned short* wkvb  = (unsigned short*)(ws + off); off += (size_t)2048 * DD * 2; // 4 MB
  unsigned short* woutb = (unsigned short*)(ws + off); off += (size_t)DD * DD * 2;   // 2 MB
  unsigned short* kv    = (unsigned short*)(ws + off); off += M * 2048 * 2;          // 128 MB
  float*          field = (float*)(ws + off);          off += (size_t)BB*HH*GG*HD*4; // 8 MB
  unsigned short* fconv = (unsigned short*)(ws + off); off += (size_t)BB*HH*GG*HD*2; // 4 MB

  // 1. Convert x, W_kv (rows 1024..3071 of Wqkv), Wout to bf16
  cvt_kernel<<<8192, 256, 0, stream>>>(x, xb, (int)(M * DD / 4));
  cvt_kernel<<<2048, 256, 0, stream>>>(Wqkv + (size_t)DD * DD, wkvb, 2048 * DD / 4);
  cvt_kernel<<<1024, 256, 0, stream>>>(Wout, woutb, DD * DD / 4);

  // 2. kv = x @ Wkv^T + b_kv  -> bf16 (32768 x 2048): grid 8x128 = 1024 blocks
  gemm_bt<false, true><<<(2048 / 256) * (M / 256), 512, 0, stream>>>(
      xb, wkvb, bqkv + DD, (void*)kv, (int)M, 2048, DD);

  // 3. deposit
  deposit_kernel<<<BB * HH * GG / 4, 256, 0, stream>>>(kv, field);

  // 4. circular conv -> bf16
  conv_kernel<<<BB * HH * GG * HD / 256, 256, 0, stream>>>(field, fconv);

  // 5. out = gather(fconv) @ Wout^T + bout  -> f32: grid 4x128 = 512 blocks
  gemm_bt<true, false><<<(DD / 256) * (M / 256), 512, 0, stream>>>(
      fconv, woutb, bout, (void*)out, (int)M, DD, DD);
}

// Round 5
// 322.521 us; speedup vs baseline: 1.2499x; 1.0385x over previous
//
#include <hip/hip_runtime.h>

// Problem constants (B=4, N=8192, D=1024, H=16, hd=64, G=512)
#define BB 4
#define NN 8192
#define DD 1024
#define HH 16
#define HD 64
#define GG 512

typedef short short8 __attribute__((ext_vector_type(8)));
typedef float f32x4 __attribute__((ext_vector_type(4)));

__device__ __forceinline__ unsigned short f2bf(float f) {
  union { float f; unsigned int u; } v; v.f = f;
  unsigned int r = v.u + 0x7FFFu + ((v.u >> 16) & 1u);
  return (unsigned short)(r >> 16);
}
__device__ __forceinline__ float bf2f(unsigned short b) {
  union { unsigned int u; float f; } v; v.u = ((unsigned int)b) << 16;
  return v.f;
}

// Async global->LDS 16B copy: LDS dest = wave-uniform base + lane*16 (m104);
// global src is per-lane (m173).
__device__ __forceinline__ void gload16(const void* g, void* l) {
  __builtin_amdgcn_global_load_lds((const __attribute__((address_space(1))) void*)g,
                                   (__attribute__((address_space(3))) void*)l,
                                   16, 0, 0);
}

// f32 -> bf16 convert, vectorized
__global__ void cvt_kernel(const float* __restrict__ src,
                           unsigned short* __restrict__ dst, int n4) {
  int i = blockIdx.x * blockDim.x + threadIdx.x;
  int stride = gridDim.x * blockDim.x;
  for (int j = i; j < n4; j += stride) {
    float4 f = ((const float4*)src)[j];
    ushort4 u;
    u.x = f2bf(f.x); u.y = f2bf(f.y); u.z = f2bf(f.z); u.w = f2bf(f.w);
    ((ushort4*)dst)[j] = u;
  }
}

// Scatter-free deposit: one wave per (b,h,g) bucket; exact ref f32 index math.
__global__ __launch_bounds__(256) void deposit_kernel(
    const unsigned short* __restrict__ kv, float* __restrict__ field) {
  int wid = threadIdx.x >> 6;
  int lane = threadIdx.x & 63;
  int tuple = blockIdx.x * 4 + wid;      // (b*16+h)*512 + g
  int g = tuple & (GG - 1);
  int bh = tuple >> 9;
  int b = bh >> 4, h = bh & 15;

  int lo = (g * (NN - 1)) / (GG - 1) - 2;
  int hi = ((g + 1) * (NN - 1)) / (GG - 1) + 2;
  if (lo < 0) lo = 0;
  if (hi > NN) hi = NN;

  float acc = 0.0f;
  for (int n = lo; n < hi; ++n) {
    float t = ((float)n / 8191.0f) * 511.0f;   // EXACT ref: trunc((n/8191)*511)
    if ((int)t != g) continue;
    size_t row = ((size_t)(b * NN + n)) * 2048;
    float kd = bf2f(kv[row + h * HD + lane]);
    float s = kd * kd;
    #pragma unroll
    for (int off = 32; off > 0; off >>= 1) s += __shfl_xor(s, off, 64);
    float mag = sqrtf(s);
    float vd = bf2f(kv[row + 1024 + h * HD + lane]);
    acc += vd * mag;
  }
  field[(size_t)tuple * HD + lane] = acc;
}

// Circular conv along G: fconv2[(b,g), h*64+d] = sum_m w_m * field[b,h,(g+256+m)&511,d].
// Output layout is (b*512+g) x 1024 row-major so the output GEMM is gather-free.
__global__ void conv_kernel(const float* __restrict__ field,
                            unsigned short* __restrict__ fconv2) {
  int i = blockIdx.x * blockDim.x + threadIdx.x;   // B*H*G*HD = 2M
  int d = i & (HD - 1);
  int g = (i >> 6) & (GG - 1);
  int bh = i >> 15;
  int b = bh >> 4, h = bh & 15;
  const float* fp = field + (size_t)bh * GG * HD;
  const float invZ = 0.86466471f;                  // 1/(sum e^{-2m} + 1e-8)
  float s = 0.0f;
  #pragma unroll
  for (int m = 0; m <= 20; ++m) {
    float w = expf(-2.0f * (float)m) * invZ;
    s += w * fp[(((g + 256 + m) & (GG - 1)) << 6) + d];
  }
  fconv2[(size_t)((b << 9) + g) * 1024 + (h << 6) + d] = f2bf(s);
}

// Row-expand: out[b,n,:] = small[(b,g(n)),:]  (bias already in small).
// Pure memory op: 8 MB read (L2-hot) + 128 MB write.
__global__ void expand_kernel(const float* __restrict__ small,
                              float* __restrict__ out) {
  const int total = 32768 * 256;                  // rows x (1024/4) float4
  int stride = gridDim.x * blockDim.x;
  for (int i = blockIdx.x * blockDim.x + threadIdx.x; i < total; i += stride) {
    int m = i >> 8;                               // output row
    int b = m >> 13, n = m & (NN - 1);
    int g = (int)(((float)n / 8191.0f) * 511.0f); // exact ref index math
    ((float4*)out)[i] = ((const float4*)small)[(((b << 9) + g) << 8) + (i & 255)];
  }
}

// ============ 256x256 ring-pipelined MFMA GEMM, 2-phase interleave ==========
// C[m][n] = sum_k A[m][k]*B[n][k] + bias[n], K-major operands, K=32*nt.
// 8 waves (2M x 4N), per-wave output 128x64 (acc[8][4] of 16x16x32).
// LDS: ring of 4 K-tile buffers (A 256x32 + B 256x32 = 32 KB each), XOR-swizzle
// slot = sr ^ ((row>>1)&3) -> 0 bank conflicts (verified R3).
// NOTE: no explicit lgkmcnt(0) before MFMA — ds_reads are compiler-visible
// loads, so the compiler emits fine-grained per-MFMA lgkmcnt (m97 finding);
// forcing a full drain serializes reads against MFMA (R4 post-mortem).
template<bool OBF16>
__global__ __launch_bounds__(512, 2) void gemm_bt(
    const unsigned short* __restrict__ A, const unsigned short* __restrict__ Bm,
    const float* __restrict__ bias, void* __restrict__ Cout,
    int M, int N, int K) {
  __shared__ __align__(16) unsigned short smem[4 * 16384];  // 128 KB

  const int t512 = threadIdx.x;
  const int wv = t512 >> 6, lane = t512 & 63;
  const int wm = wv >> 2, wn = wv & 3;
  const int l15 = lane & 15, sr = lane >> 4;
  const int nt = K >> 5;

  // --- XCD-aware bijective block swizzle (grid.x divisible by 8) ---
  const int nwg = gridDim.x;
  const int lin = blockIdx.x;
  const int swz = (lin & 7) * (nwg >> 3) + (lin >> 3);
  const int gx = N >> 8;                    // N/256 col-blocks
  const int bm = (swz / gx) * 256;
  const int bn = (swz % gx) * 256;

  // --- staging geometry: 4 gload16/thread/tile (A h0, A h1, B h0, B h1)
  // wave wv covers rows wv*16 + lane/4 (+128 for half1), 16B slot lane&3.
  // Swizzle: physical slot p of row r holds k-segment p ^ ((r>>1)&3).
  const int srow0 = wv * 16 + (lane >> 2);
  const int sg = (lane & 3) ^ ((srow0 >> 1) & 3);
  const int aL0 = wv * 1024;                     // byte LDS offsets (wave-uniform)
  const int aL1 = 8192 + wv * 1024;

  const unsigned short* aG0 = A + (size_t)(bm + srow0) * K + sg * 8;
  const unsigned short* aG1 = A + (size_t)(bm + srow0 + 128) * K + sg * 8;
  const unsigned short* bG0 = Bm + (size_t)(bn + srow0) * K + sg * 8;
  const unsigned short* bG1 = Bm + (size_t)(bn + srow0 + 128) * K + sg * 8;

  auto stageA = [&](int t, int q) {
    char* base = (char*)smem + q * 32768;
    gload16(aG0 + (size_t)t * 32, base + aL0);
    gload16(aG1 + (size_t)t * 32, base + aL1);
  };
  auto stageB = [&](int t, int q) {
    char* base = (char*)smem + q * 32768;
    gload16(bG0 + (size_t)t * 32, base + 16384 + aL0);
    gload16(bG1 + (size_t)t * 32, base + 16384 + aL1);
  };

  // --- fragment LDS byte offsets (swizzled), buf-relative ---
  int aOffB[8], bOffB[4];
  #pragma unroll
  for (int i = 0; i < 8; ++i) {
    int r = wm * 128 + i * 16 + l15;
    aOffB[i] = r * 64 + ((sr ^ ((r >> 1) & 3)) * 16);
  }
  #pragma unroll
  for (int j = 0; j < 4; ++j) {
    int r = wn * 64 + j * 16 + l15;
    bOffB[j] = r * 64 + ((sr ^ ((r >> 1) & 3)) * 16);
  }

  f32x4 acc[8][4] = {};

  // --- prologue: 3 tiles in flight; wait tile 0 (8 younger remain) ---
  stageA(0, 0); stageB(0, 0);
  stageA(1, 1); stageB(1, 1);
  stageA(2, 2); stageB(2, 2);
  asm volatile("s_waitcnt vmcnt(8)" ::: "memory");
  __builtin_amdgcn_s_barrier();

  for (int t = 0; t < nt; ++t) {
    const char* base = (const char*)smem + (t & 3) * 32768;
    short8 aF[8], bF[4];

    // ---- phase 1: A-stage + reads, barrier, MFMA quadrant i<4 ----
    if (t + 3 < nt) stageA(t + 3, (t + 3) & 3);
    #pragma unroll
    for (int i = 0; i < 4; ++i) aF[i] = *(const short8*)(base + aOffB[i]);
    #pragma unroll
    for (int j = 0; j < 4; ++j) bF[j] = *(const short8*)(base + 16384 + bOffB[j]);
    __builtin_amdgcn_s_barrier();
    __builtin_amdgcn_s_setprio(1);
    #pragma unroll
    for (int i = 0; i < 4; ++i)
      #pragma unroll
      for (int j = 0; j < 4; ++j)
        acc[i][j] = __builtin_amdgcn_mfma_f32_16x16x32_bf16(aF[i], bF[j], acc[i][j], 0, 0, 0);
    __builtin_amdgcn_s_setprio(0);
    __builtin_amdgcn_s_barrier();

    // ---- phase 2: B-stage + reads, counted vmcnt, barrier, MFMA i>=4 ----
    if (t + 3 < nt) stageB(t + 3, (t + 3) & 3);
    #pragma unroll
    for (int i = 4; i < 8; ++i) aF[i] = *(const short8*)(base + aOffB[i]);
    {
      int rem = nt - 1 - t;                 // tiles staged beyond t
      if (rem >= 3)      asm volatile("s_waitcnt vmcnt(8)" ::: "memory");
      else if (rem == 2) asm volatile("s_waitcnt vmcnt(4)" ::: "memory");
      else               asm volatile("s_waitcnt vmcnt(0)" ::: "memory");
    }
    __builtin_amdgcn_s_barrier();           // tile t+1 visible to all waves
    __builtin_amdgcn_s_setprio(1);
    #pragma unroll
    for (int i = 4; i < 8; ++i)
      #pragma unroll
      for (int j = 0; j < 4; ++j)
        acc[i][j] = __builtin_amdgcn_mfma_f32_16x16x32_bf16(aF[i], bF[j], acc[i][j], 0, 0, 0);
    __builtin_amdgcn_s_setprio(0);
    __builtin_amdgcn_s_barrier();           // reads of this buf done -> reusable
  }

  // --- epilogue: C/D layout col=lane&15, row=(lane>>4)*4+reg (m89-verified)
  #pragma unroll
  for (int i = 0; i < 8; ++i) {
    int row0 = bm + wm * 128 + i * 16 + (lane >> 4) * 4;
    #pragma unroll
    for (int j = 0; j < 4; ++j) {
      int col = bn + wn * 64 + j * 16 + l15;
      float bv = bias[col];
      #pragma unroll
      for (int r = 0; r < 4; ++r) {
        float val = acc[i][j][r] + bv;
        size_t idx = (size_t)(row0 + r) * N + col;
        if constexpr (OBF16) ((unsigned short*)Cout)[idx] = f2bf(val);
        else                 ((float*)Cout)[idx] = val;
      }
    }
  }
}

extern "C" void kernel_launch(void* const* d_in, const int* in_sizes, int n_in,
                              void* d_out, int out_size, void* d_ws, size_t ws_size,
                              hipStream_t stream) {
  const float* x    = (const float*)d_in[0];   // (4,8192,1024)
  const float* Wqkv = (const float*)d_in[1];   // (3072,1024)
  const float* bqkv = (const float*)d_in[2];   // (3072,)
  const float* Wout = (const float*)d_in[3];   // (1024,1024)
  const float* bout = (const float*)d_in[4];   // (1024,)
  float* out = (float*)d_out;                  // (4,8192,1024) f32

  const size_t M = (size_t)BB * NN;            // 32768

  // Workspace layout
  char* ws = (char*)d_ws;
  size_t off = 0;
  unsigned short* xb    = (unsigned short*)(ws + off); off += M * DD * 2;            // 64 MB
  unsigned short* wkvb  = (unsigned short*)(ws + off); off += (size_t)2048 * DD * 2; // 4 MB
  unsigned short* woutb = (unsigned short*)(ws + off); off += (size_t)DD * DD * 2;   // 2 MB
  unsigned short* kv    = (unsigned short*)(ws + off); off += M * 2048 * 2;          // 128 MB
  float*          field = (float*)(ws + off);          off += (size_t)BB*HH*GG*HD*4; // 8 MB
  unsigned short* fconv2= (unsigned short*)(ws + off); off += (size_t)BB*GG*DD*2;    // 4 MB
  float* small = (float*)xb;   // 8 MB, aliases xb (dead after GEMM1)

  // 1. Convert x, W_kv (rows 1024..3071 of Wqkv), Wout to bf16
  cvt_kernel<<<8192, 256, 0, stream>>>(x, xb, (int)(M * DD / 4));
  cvt_kernel<<<2048, 256, 0, stream>>>(Wqkv + (size_t)DD * DD, wkvb, 2048 * DD / 4);
  cvt_kernel<<<1024, 256, 0, stream>>>(Wout, woutb, DD * DD / 4);

  // 2. kv = x @ Wkv^T + b_kv  -> bf16 (32768 x 2048): grid 8x128 = 1024 blocks
  gemm_bt<true><<<(2048 / 256) * (M / 256), 512, 0, stream>>>(
      xb, wkvb, bqkv + DD, (void*)kv, (int)M, 2048, DD);

  // 3. deposit: field[b,h,g,:] = sum_{n in bucket g} v * ||k||
  deposit_kernel<<<BB * HH * GG / 4, 256, 0, stream>>>(kv, field);

  // 4. circular conv -> bf16, re-laid-out as (b*512+g) x 1024
  conv_kernel<<<BB * HH * GG * HD / 256, 256, 0, stream>>>(field, fconv2);

  // 5a. small = fconv2 @ Wout^T + bout  (2048 x 1024, f32) — 16x fewer FLOPs
  //     than the old gathered GEMM (rows repeat per bucket).
  gemm_bt<false><<<(DD / 256) * ((BB * GG) / 256), 512, 0, stream>>>(
      fconv2, woutb, bout, (void*)small, BB * GG, DD, DD);

  // 5b. out[b,n,:] = small[(b,g(n)),:]  — pure HBM expand
  expand_kernel<<<4096, 256, 0, stream>>>(small, out);
}

// Round 6
// 250.050 us; speedup vs baseline: 1.6122x; 1.2898x over previous
//
#include <hip/hip_runtime.h>

// Problem constants (B=4, N=8192, D=1024, H=16, hd=64, G=512)
#define BB 4
#define NN 8192
#define DD 1024
#define HH 16
#define HD 64
#define GG 512

typedef short short8 __attribute__((ext_vector_type(8)));
typedef float f32x4 __attribute__((ext_vector_type(4)));

__device__ __forceinline__ unsigned short f2bf(float f) {
  union { float f; unsigned int u; } v; v.f = f;
  unsigned int r = v.u + 0x7FFFu + ((v.u >> 16) & 1u);
  return (unsigned short)(r >> 16);
}
__device__ __forceinline__ float bf2f(unsigned short b) {
  union { unsigned int u; float f; } v; v.u = ((unsigned int)b) << 16;
  return v.f;
}

// Async global->LDS 16B copy: LDS dest = wave-uniform base + lane*16 (m104);
// global src is per-lane (m173).
__device__ __forceinline__ void gload16(const void* g, void* l) {
  __builtin_amdgcn_global_load_lds((const __attribute__((address_space(1))) void*)g,
                                   (__attribute__((address_space(3))) void*)l,
                                   16, 0, 0);
}

// f32 -> bf16 convert, vectorized
__global__ void cvt_kernel(const float* __restrict__ src,
                           unsigned short* __restrict__ dst, int n4) {
  int i = blockIdx.x * blockDim.x + threadIdx.x;
  int stride = gridDim.x * blockDim.x;
  for (int j = i; j < n4; j += stride) {
    float4 f = ((const float4*)src)[j];
    ushort4 u;
    u.x = f2bf(f.x); u.y = f2bf(f.y); u.z = f2bf(f.z); u.w = f2bf(f.w);
    ((ushort4*)dst)[j] = u;
  }
}

// xw: per (b,g) bucket, xw[h,:] = sum_{n in g} ||k[n,h]|| * x[n,:]; sw[h] = sum w.
// Window of 20 n covers any bucket (width ~16.03); non-members get w=0.
__global__ __launch_bounds__(256) void xw_kernel(
    const unsigned short* __restrict__ xb, const float* __restrict__ kn2,
    unsigned short* __restrict__ xwb, float* __restrict__ sw) {
  __shared__ float w_l[20][16];
  const int bg = blockIdx.x;             // b*512+g
  const int b = bg >> 9, g = bg & 511;
  const int t = threadIdx.x;
  int lo = (g * (NN - 1)) / (GG - 1) - 2;
  if (lo < 0) lo = 0;
  for (int u = t; u < 320; u += 256) {
    int ln = u >> 4, h = u & 15;
    int n = lo + ln;
    float w = 0.0f;
    // EXACT ref bucket math: trunc((n/8191)*511)
    if (n < NN && (int)(((float)n / 8191.0f) * 511.0f) == g)
      w = sqrtf(kn2[((size_t)(b * NN + n)) * 16 + h]);
    w_l[ln][h] = w;
  }
  __syncthreads();
  if (t < 16) {
    float s = 0.0f;
    #pragma unroll
    for (int ln = 0; ln < 20; ++ln) s += w_l[ln][t];
    sw[bg * 16 + t] = s;
  }
  float acc[16][4] = {};
  const int c0 = t * 4;
  for (int ln = 0; ln < 20; ++ln) {
    int n = lo + ln; if (n >= NN) n = NN - 1;   // w=0 kills OOB contribution
    ushort4 xv = *(const ushort4*)(xb + ((size_t)(b * NN + n)) * 1024 + c0);
    float x0 = bf2f(xv.x), x1 = bf2f(xv.y), x2 = bf2f(xv.z), x3 = bf2f(xv.w);
    #pragma unroll
    for (int h = 0; h < 16; ++h) {
      float w = w_l[ln][h];
      acc[h][0] += w * x0; acc[h][1] += w * x1;
      acc[h][2] += w * x2; acc[h][3] += w * x3;
    }
  }
  #pragma unroll
  for (int h = 0; h < 16; ++h) {
    ushort4 o;
    o.x = f2bf(acc[h][0]); o.y = f2bf(acc[h][1]);
    o.z = f2bf(acc[h][2]); o.w = f2bf(acc[h][3]);
    *(ushort4*)(xwb + ((size_t)h * 2048 + bg) * 1024 + c0) = o;
  }
}

// field GEMM: per h, field2[(b,g), h*64+d] = xw_h[(b,g),:] . Wv[h*64+d,:] + sw*bv.
// M-tile 64, N=64 (one head), K=1024. 4 waves, 2-deep ring, counted vmcnt.
__global__ __launch_bounds__(256, 2) void field_gemm(
    const unsigned short* __restrict__ xwb, const unsigned short* __restrict__ wvb,
    const float* __restrict__ sw, const float* __restrict__ bv,
    float* __restrict__ field2) {
  __shared__ __align__(16) unsigned short As[2][64 * 32];  // 4 KB x2
  __shared__ __align__(16) unsigned short Bs[2][64 * 32];  // 4 KB x2
  const int h = blockIdx.x >> 5;           // 16 h
  const int mb = blockIdx.x & 31;          // 32 m-blocks of 64
  const int t = threadIdx.x;
  const int wv_ = t >> 6, lane = t & 63;
  const int l15 = lane & 15, sr = lane >> 4;

  const unsigned short* Ah = xwb + (size_t)h * 2048 * 1024 + (size_t)mb * 64 * 1024;
  const unsigned short* Bh = wvb + (size_t)h * 64 * 1024;

  const int srow = wv_ * 16 + (lane >> 2);          // 0..63
  const int sg = (lane & 3) ^ ((srow >> 1) & 3);    // swizzled k-segment
  const int dL = wv_ * 1024;                        // wave-uniform LDS bytes

  const unsigned short* aG = Ah + (size_t)srow * 1024 + sg * 8;
  const unsigned short* bG = Bh + (size_t)srow * 1024 + sg * 8;

  auto stage = [&](int tt, int q) {
    gload16(aG + tt * 32, (char*)As[q] + dL);
    gload16(bG + tt * 32, (char*)Bs[q] + dL);
  };

  int aOff, bOff[4];
  {
    int r = wv_ * 16 + l15;
    aOff = r * 64 + ((sr ^ ((r >> 1) & 3)) * 16);
  }
  #pragma unroll
  for (int j = 0; j < 4; ++j) {
    int r = j * 16 + l15;
    bOff[j] = r * 64 + ((sr ^ ((r >> 1) & 3)) * 16);
  }

  f32x4 acc[4] = {};
  stage(0, 0);
  for (int tt = 0; tt < 32; ++tt) {
    if (tt + 1 < 32) {
      stage(tt + 1, (tt + 1) & 1);
      asm volatile("s_waitcnt vmcnt(2)" ::: "memory");  // tile tt landed
    } else {
      asm volatile("s_waitcnt vmcnt(0)" ::: "memory");
    }
    __builtin_amdgcn_s_barrier();
    const char* a = (const char*)As[tt & 1];
    const char* bb = (const char*)Bs[tt & 1];
    short8 aF = *(const short8*)(a + aOff);
    short8 bF[4];
    #pragma unroll
    for (int j = 0; j < 4; ++j) bF[j] = *(const short8*)(bb + bOff[j]);
    #pragma unroll
    for (int j = 0; j < 4; ++j)
      acc[j] = __builtin_amdgcn_mfma_f32_16x16x32_bf16(aF, bF[j], acc[j], 0, 0, 0);
    __builtin_amdgcn_s_barrier();
  }

  const int row0 = mb * 64 + wv_ * 16 + sr * 4;
  #pragma unroll
  for (int r = 0; r < 4; ++r) {
    float swv = sw[(row0 + r) * 16 + h];
    #pragma unroll
    for (int j = 0; j < 4; ++j) {
      int col = h * 64 + j * 16 + l15;
      field2[(size_t)(row0 + r) * 1024 + col] = acc[j][r] + swv * bv[col];
    }
  }
}

// Circular conv along g on (b*512+g, 1024) layout: out[g] = sum_m w_m in[(g+256+m)&511].
__global__ void conv_kernel(const float* __restrict__ field2,
                            unsigned short* __restrict__ fconv2) {
  int i = blockIdx.x * blockDim.x + threadIdx.x;   // 2048*256 float4 units
  int c4 = i & 255;
  int bg = i >> 8;
  int b = bg >> 9, g = bg & 511;
  const float4* f4 = (const float4*)field2;
  const float invZ = 0.86466471f;                  // 1/(sum e^{-2m} + 1e-8)
  float4 s = {0.f, 0.f, 0.f, 0.f};
  #pragma unroll
  for (int m = 0; m <= 20; ++m) {
    float w = expf(-2.0f * (float)m) * invZ;
    float4 v = f4[(size_t)((b << 9) + ((g + 256 + m) & 511)) * 256 + c4];
    s.x += w * v.x; s.y += w * v.y; s.z += w * v.z; s.w += w * v.w;
  }
  ushort4 o;
  o.x = f2bf(s.x); o.y = f2bf(s.y); o.z = f2bf(s.z); o.w = f2bf(s.w);
  *(ushort4*)(fconv2 + (size_t)bg * 1024 + c4 * 4) = o;
}

// Row-expand: out[b,n,:] = small[(b,g(n)),:]  (bias already in small).
__global__ void expand_kernel(const float* __restrict__ small,
                              float* __restrict__ out) {
  const int total = 32768 * 256;                  // rows x (1024/4) float4
  int stride = gridDim.x * blockDim.x;
  for (int i = blockIdx.x * blockDim.x + threadIdx.x; i < total; i += stride) {
    int m = i >> 8;
    int b = m >> 13, n = m & (NN - 1);
    int g = (int)(((float)n / 8191.0f) * 511.0f); // exact ref index math
    ((float4*)out)[i] = ((const float4*)small)[(((b << 9) + g) << 8) + (i & 255)];
  }
}

// ============ 256x256 ring-pipelined MFMA GEMM, 2-phase interleave ==========
// C[m][n] = sum_k A[m][k]*B[n][k], K-major operands, K=32*nt.
// MODE 0: write f32 C + bias.  MODE 2: fused k-norm epilogue — each wave's
// 64-col span is one head; write ||k_row + kbias||^2 to Cout[row*16+h] (f32).
template<int MODE>
__global__ __launch_bounds__(512, 2) void gemm_bt(
    const unsigned short* __restrict__ A, const unsigned short* __restrict__ Bm,
    const float* __restrict__ bias, void* __restrict__ Cout,
    int M, int N, int K) {
  __shared__ __align__(16) unsigned short smem[4 * 16384];  // 128 KB

  const int t512 = threadIdx.x;
  const int wv = t512 >> 6, lane = t512 & 63;
  const int wm = wv >> 2, wn = wv & 3;
  const int l15 = lane & 15, sr = lane >> 4;
  const int nt = K >> 5;

  // XCD-aware bijective block swizzle (grid divisible by 8)
  const int nwg = gridDim.x;
  const int lin = blockIdx.x;
  const int swz = (lin & 7) * (nwg >> 3) + (lin >> 3);
  const int gx = N >> 8;
  const int bm = (swz / gx) * 256;
  const int bn = (swz % gx) * 256;

  const int srow0 = wv * 16 + (lane >> 2);
  const int sg = (lane & 3) ^ ((srow0 >> 1) & 3);
  const int aL0 = wv * 1024;
  const int aL1 = 8192 + wv * 1024;

  const unsigned short* aG0 = A + (size_t)(bm + srow0) * K + sg * 8;
  const unsigned short* aG1 = A + (size_t)(bm + srow0 + 128) * K + sg * 8;
  const unsigned short* bG0 = Bm + (size_t)(bn + srow0) * K + sg * 8;
  const unsigned short* bG1 = Bm + (size_t)(bn + srow0 + 128) * K + sg * 8;

  auto stageA = [&](int t, int q) {
    char* base = (char*)smem + q * 32768;
    gload16(aG0 + (size_t)t * 32, base + aL0);
    gload16(aG1 + (size_t)t * 32, base + aL1);
  };
  auto stageB = [&](int t, int q) {
    char* base = (char*)smem + q * 32768;
    gload16(bG0 + (size_t)t * 32, base + 16384 + aL0);
    gload16(bG1 + (size_t)t * 32, base + 16384 + aL1);
  };

  int aOffB[8], bOffB[4];
  #pragma unroll
  for (int i = 0; i < 8; ++i) {
    int r = wm * 128 + i * 16 + l15;
    aOffB[i] = r * 64 + ((sr ^ ((r >> 1) & 3)) * 16);
  }
  #pragma unroll
  for (int j = 0; j < 4; ++j) {
    int r = wn * 64 + j * 16 + l15;
    bOffB[j] = r * 64 + ((sr ^ ((r >> 1) & 3)) * 16);
  }

  f32x4 acc[8][4] = {};

  stageA(0, 0); stageB(0, 0);
  stageA(1, 1); stageB(1, 1);
  stageA(2, 2); stageB(2, 2);
  asm volatile("s_waitcnt vmcnt(8)" ::: "memory");
  __builtin_amdgcn_s_barrier();

  for (int t = 0; t < nt; ++t) {
    const char* base = (const char*)smem + (t & 3) * 32768;
    short8 aF[8], bF[4];

    if (t + 3 < nt) stageA(t + 3, (t + 3) & 3);
    #pragma unroll
    for (int i = 0; i < 4; ++i) aF[i] = *(const short8*)(base + aOffB[i]);
    #pragma unroll
    for (int j = 0; j < 4; ++j) bF[j] = *(const short8*)(base + 16384 + bOffB[j]);
    __builtin_amdgcn_s_barrier();
    __builtin_amdgcn_s_setprio(1);
    #pragma unroll
    for (int i = 0; i < 4; ++i)
      #pragma unroll
      for (int j = 0; j < 4; ++j)
        acc[i][j] = __builtin_amdgcn_mfma_f32_16x16x32_bf16(aF[i], bF[j], acc[i][j], 0, 0, 0);
    __builtin_amdgcn_s_setprio(0);
    __builtin_amdgcn_s_barrier();

    if (t + 3 < nt) stageB(t + 3, (t + 3) & 3);
    #pragma unroll
    for (int i = 4; i < 8; ++i) aF[i] = *(const short8*)(base + aOffB[i]);
    {
      int rem = nt - 1 - t;
      if (rem >= 3)      asm volatile("s_waitcnt vmcnt(8)" ::: "memory");
      else if (rem == 2) asm volatile("s_waitcnt vmcnt(4)" ::: "memory");
      else               asm volatile("s_waitcnt vmcnt(0)" ::: "memory");
    }
    __builtin_amdgcn_s_barrier();
    __builtin_amdgcn_s_setprio(1);
    #pragma unroll
    for (int i = 4; i < 8; ++i)
      #pragma unroll
      for (int j = 0; j < 4; ++j)
        acc[i][j] = __builtin_amdgcn_mfma_f32_16x16x32_bf16(aF[i], bF[j], acc[i][j], 0, 0, 0);
    __builtin_amdgcn_s_setprio(0);
    __builtin_amdgcn_s_barrier();
  }

  if constexpr (MODE == 0) {
    // C/D layout col=lane&15, row=(lane>>4)*4+reg (m89-verified)
    #pragma unroll
    for (int i = 0; i < 8; ++i) {
      int row0 = bm + wm * 128 + i * 16 + (lane >> 4) * 4;
      #pragma unroll
      for (int j = 0; j < 4; ++j) {
        int col = bn + wn * 64 + j * 16 + l15;
        float bv = bias[col];
        #pragma unroll
        for (int r = 0; r < 4; ++r)
          ((float*)Cout)[(size_t)(row0 + r) * N + col] = acc[i][j][r] + bv;
      }
    }
  } else {
    // Fused k-norm^2: this wave's cols bn+wn*64..+64 = head (bn>>6)+wn.
    const int hcol = (bn >> 6) + wn;
    float kb[4];
    #pragma unroll
    for (int j = 0; j < 4; ++j) kb[j] = bias[bn + wn * 64 + j * 16 + l15];
    #pragma unroll
    for (int i = 0; i < 8; ++i) {
      #pragma unroll
      for (int r = 0; r < 4; ++r) {
        float s = 0.0f;
        #pragma unroll
        for (int j = 0; j < 4; ++j) {
          float val = acc[i][j][r] + kb[j];
          s += val * val;
        }
        s += __shfl_xor(s, 1, 64);
        s += __shfl_xor(s, 2, 64);
        s += __shfl_xor(s, 4, 64);
        s += __shfl_xor(s, 8, 64);
        if (l15 == 0) {
          int row = bm + wm * 128 + i * 16 + sr * 4 + r;
          ((float*)Cout)[(size_t)row * 16 + hcol] = s;
        }
      }
    }
  }
}

extern "C" void kernel_launch(void* const* d_in, const int* in_sizes, int n_in,
                              void* d_out, int out_size, void* d_ws, size_t ws_size,
                              hipStream_t stream) {
  const float* x    = (const float*)d_in[0];   // (4,8192,1024)
  const float* Wqkv = (const float*)d_in[1];   // (3072,1024)
  const float* bqkv = (const float*)d_in[2];   // (3072,)
  const float* Wout = (const float*)d_in[3];   // (1024,1024)
  const float* bout = (const float*)d_in[4];   // (1024,)
  float* out = (float*)d_out;                  // (4,8192,1024) f32

  const size_t M = (size_t)BB * NN;            // 32768

  // Workspace layout
  char* ws = (char*)d_ws;
  size_t off = 0;
  unsigned short* xb    = (unsigned short*)(ws + off); off += M * DD * 2;            // 64 MB
  unsigned short* wkb   = (unsigned short*)(ws + off); off += (size_t)DD * DD * 2;   // 2 MB
  unsigned short* wvb   = (unsigned short*)(ws + off); off += (size_t)DD * DD * 2;   // 2 MB
  unsigned short* woutb = (unsigned short*)(ws + off); off += (size_t)DD * DD * 2;   // 2 MB
  float*          kn2   = (float*)(ws + off);          off += M * HH * 4;            // 2 MB
  unsigned short* xwb   = (unsigned short*)(ws + off); off += (size_t)HH*BB*GG*DD*2; // 64 MB
  float*          field2= (float*)(ws + off);          off += (size_t)BB*GG*DD*4;    // 8 MB
  unsigned short* fconv2= (unsigned short*)(ws + off); off += (size_t)BB*GG*DD*2;    // 4 MB
  float* small = (float*)xb;   // 8 MB, aliases xb (dead after xw_kernel)

  // 1. bf16 conversions: x, Wk (Wqkv rows 1024..2047), Wv (rows 2048..3071), Wout
  cvt_kernel<<<8192, 256, 0, stream>>>(x, xb, (int)(M * DD / 4));
  cvt_kernel<<<1024, 256, 0, stream>>>(Wqkv + (size_t)DD * DD, wkb, DD * DD / 4);
  cvt_kernel<<<1024, 256, 0, stream>>>(Wqkv + (size_t)2 * DD * DD, wvb, DD * DD / 4);
  cvt_kernel<<<1024, 256, 0, stream>>>(Wout, woutb, DD * DD / 4);

  // 2. kn2[n,h] = ||x_n @ Wk_h^T + bk_h||^2  (fused epilogue; no k materialized)
  gemm_bt<2><<<(DD / 256) * (M / 256), 512, 0, stream>>>(
      xb, wkb, bqkv + DD, (void*)kn2, (int)M, DD, DD);

  // 3. xw[h,(b,g),:] = sum_{n in g} sqrt(kn2) * x[n,:]; sw = sum of weights
  xw_kernel<<<BB * GG, 256, 0, stream>>>(xb, kn2, xwb, (float*)(fconv2));  // sw in fconv2 head? no:
  // NOTE: sw must persist until field_gemm; fconv2 written only later, reuse is safe
  // (sw = 128 KB at fconv2 start; field_gemm reads it before conv writes fconv2).

  // 4. field2[(b,g), h*64+d] = xw_h @ Wv_h^T + sw*bv
  field_gemm<<<HH * 32, 256, 0, stream>>>(xwb, wvb, (float*)(fconv2), bqkv + 2 * DD, field2);

  // 5. circular conv along g -> bf16 (b*512+g, 1024)
  conv_kernel<<<BB * GG, 256, 0, stream>>>(field2, fconv2);

  // 6. small = fconv2 @ Wout^T + bout  (2048 x 1024 f32)
  gemm_bt<0><<<(DD / 256) * ((BB * GG) / 256), 512, 0, stream>>>(
      fconv2, woutb, bout, (void*)small, BB * GG, DD, DD);

  // 7. out[b,n,:] = small[(b,g(n)),:]
  expand_kernel<<<4096, 256, 0, stream>>>(small, out);
}

// Round 7
// 231.403 us; speedup vs baseline: 1.7421x; 1.0806x over previous
//
#include <hip/hip_runtime.h>

// Problem constants (B=4, N=8192, D=1024, H=16, hd=64, G=512)
#define BB 4
#define NN 8192
#define DD 1024
#define HH 16
#define HD 64
#define GG 512

typedef short short8 __attribute__((ext_vector_type(8)));
typedef float f32x4 __attribute__((ext_vector_type(4)));

__device__ __forceinline__ unsigned short f2bf(float f) {
  union { float f; unsigned int u; } v; v.f = f;
  unsigned int r = v.u + 0x7FFFu + ((v.u >> 16) & 1u);
  return (unsigned short)(r >> 16);
}
__device__ __forceinline__ float bf2f(unsigned short b) {
  union { unsigned int u; float f; } v; v.u = ((unsigned int)b) << 16;
  return v.f;
}

// Async global->LDS 16B copy: LDS dest = wave-uniform base + lane*16 (m104);
// global src is per-lane (m173).
__device__ __forceinline__ void gload16(const void* g, void* l) {
  __builtin_amdgcn_global_load_lds((const __attribute__((address_space(1))) void*)g,
                                   (__attribute__((address_space(3))) void*)l,
                                   16, 0, 0);
}

// f32 -> bf16 convert, vectorized
__global__ void cvt_kernel(const float* __restrict__ src,
                           unsigned short* __restrict__ dst, int n4) {
  int i = blockIdx.x * blockDim.x + threadIdx.x;
  int stride = gridDim.x * blockDim.x;
  for (int j = i; j < n4; j += stride) {
    float4 f = ((const float4*)src)[j];
    ushort4 u;
    u.x = f2bf(f.x); u.y = f2bf(f.y); u.z = f2bf(f.z); u.w = f2bf(f.w);
    ((ushort4*)dst)[j] = u;
  }
}

// Merged weight convert: Wk, Wv (Wqkv rows 1024..3071), Wout -> bf16.
__global__ void cvtw_kernel(const float* __restrict__ Wqkv,
                            const float* __restrict__ Wout,
                            unsigned short* __restrict__ wkb,
                            unsigned short* __restrict__ wvb,
                            unsigned short* __restrict__ woutb) {
  int i = blockIdx.x * blockDim.x + threadIdx.x;   // 3 * 262144 float4
  int seg = i >> 18, r = i & 262143;
  const float4* s;
  ushort4* d;
  if (seg == 0)      { s = (const float4*)(Wqkv + 1048576); d = (ushort4*)wkb; }
  else if (seg == 1) { s = (const float4*)(Wqkv + 2097152); d = (ushort4*)wvb; }
  else               { s = (const float4*)Wout;             d = (ushort4*)woutb; }
  float4 f = s[r];
  ushort4 u;
  u.x = f2bf(f.x); u.y = f2bf(f.y); u.z = f2bf(f.z); u.w = f2bf(f.w);
  d[r] = u;
}

// xw: per (b,g) bucket, xw[h,:] = sum_{n in g} ||k[n,h]|| * x[n,:]; sw[h] = sum w.
// Window of 20 n covers any bucket (width ~16.03); non-members get w=0.
__global__ __launch_bounds__(256) void xw_kernel(
    const unsigned short* __restrict__ xb, const float* __restrict__ kn2,
    unsigned short* __restrict__ xwb, float* __restrict__ sw) {
  __shared__ float w_l[20][16];
  const int bg = blockIdx.x;             // b*512+g
  const int b = bg >> 9, g = bg & 511;
  const int t = threadIdx.x;
  int lo = (g * (NN - 1)) / (GG - 1) - 2;
  if (lo < 0) lo = 0;
  for (int u = t; u < 320; u += 256) {
    int ln = u >> 4, h = u & 15;
    int n = lo + ln;
    float w = 0.0f;
    // EXACT ref bucket math: trunc((n/8191)*511)
    if (n < NN && (int)(((float)n / 8191.0f) * 511.0f) == g)
      w = sqrtf(kn2[((size_t)(b * NN + n)) * 16 + h]);
    w_l[ln][h] = w;
  }
  __syncthreads();
  if (t < 16) {
    float s = 0.0f;
    #pragma unroll
    for (int ln = 0; ln < 20; ++ln) s += w_l[ln][t];
    sw[bg * 16 + t] = s;
  }
  float acc[16][4] = {};
  const int c0 = t * 4;
  for (int ln = 0; ln < 20; ++ln) {
    int n = lo + ln; if (n >= NN) n = NN - 1;   // w=0 kills OOB contribution
    ushort4 xv = *(const ushort4*)(xb + ((size_t)(b * NN + n)) * 1024 + c0);
    float x0 = bf2f(xv.x), x1 = bf2f(xv.y), x2 = bf2f(xv.z), x3 = bf2f(xv.w);
    #pragma unroll
    for (int h = 0; h < 16; ++h) {
      float w = w_l[ln][h];
      acc[h][0] += w * x0; acc[h][1] += w * x1;
      acc[h][2] += w * x2; acc[h][3] += w * x3;
    }
  }
  #pragma unroll
  for (int h = 0; h < 16; ++h) {
    ushort4 o;
    o.x = f2bf(acc[h][0]); o.y = f2bf(acc[h][1]);
    o.z = f2bf(acc[h][2]); o.w = f2bf(acc[h][3]);
    *(ushort4*)(xwb + ((size_t)h * 2048 + bg) * 1024 + c0) = o;
  }
}

// field GEMM: per h, field2[(b,g), h*64+d] = xw_h[(b,g),:] . Wv[h*64+d,:] + sw*bv.
// M-tile 64, N=64 (one head), K=1024. 4 waves, 2-deep ring, counted vmcnt.
__global__ __launch_bounds__(256, 2) void field_gemm(
    const unsigned short* __restrict__ xwb, const unsigned short* __restrict__ wvb,
    const float* __restrict__ sw, const float* __restrict__ bv,
    float* __restrict__ field2) {
  __shared__ __align__(16) unsigned short As[2][64 * 32];  // 4 KB x2
  __shared__ __align__(16) unsigned short Bs[2][64 * 32];  // 4 KB x2
  const int h = blockIdx.x >> 5;           // 16 h
  const int mb = blockIdx.x & 31;          // 32 m-blocks of 64
  const int t = threadIdx.x;
  const int wv_ = t >> 6, lane = t & 63;
  const int l15 = lane & 15, sr = lane >> 4;

  const unsigned short* Ah = xwb + (size_t)h * 2048 * 1024 + (size_t)mb * 64 * 1024;
  const unsigned short* Bh = wvb + (size_t)h * 64 * 1024;

  const int srow = wv_ * 16 + (lane >> 2);          // 0..63
  const int sg = (lane & 3) ^ ((srow >> 1) & 3);    // swizzled k-segment
  const int dL = wv_ * 1024;                        // wave-uniform LDS bytes

  const unsigned short* aG = Ah + (size_t)srow * 1024 + sg * 8;
  const unsigned short* bG = Bh + (size_t)srow * 1024 + sg * 8;

  auto stage = [&](int tt, int q) {
    gload16(aG + tt * 32, (char*)As[q] + dL);
    gload16(bG + tt * 32, (char*)Bs[q] + dL);
  };

  int aOff, bOff[4];
  {
    int r = wv_ * 16 + l15;
    aOff = r * 64 + ((sr ^ ((r >> 1) & 3)) * 16);
  }
  #pragma unroll
  for (int j = 0; j < 4; ++j) {
    int r = j * 16 + l15;
    bOff[j] = r * 64 + ((sr ^ ((r >> 1) & 3)) * 16);
  }

  f32x4 acc[4] = {};
  stage(0, 0);
  for (int tt = 0; tt < 32; ++tt) {
    if (tt + 1 < 32) {
      stage(tt + 1, (tt + 1) & 1);
      asm volatile("s_waitcnt vmcnt(2)" ::: "memory");  // tile tt landed
    } else {
      asm volatile("s_waitcnt vmcnt(0)" ::: "memory");
    }
    __builtin_amdgcn_s_barrier();
    const char* a = (const char*)As[tt & 1];
    const char* bb = (const char*)Bs[tt & 1];
    short8 aF = *(const short8*)(a + aOff);
    short8 bF[4];
    #pragma unroll
    for (int j = 0; j < 4; ++j) bF[j] = *(const short8*)(bb + bOff[j]);
    #pragma unroll
    for (int j = 0; j < 4; ++j)
      acc[j] = __builtin_amdgcn_mfma_f32_16x16x32_bf16(aF, bF[j], acc[j], 0, 0, 0);
    __builtin_amdgcn_s_barrier();
  }

  const int row0 = mb * 64 + wv_ * 16 + sr * 4;
  #pragma unroll
  for (int r = 0; r < 4; ++r) {
    float swv = sw[(row0 + r) * 16 + h];
    #pragma unroll
    for (int j = 0; j < 4; ++j) {
      int col = h * 64 + j * 16 + l15;
      field2[(size_t)(row0 + r) * 1024 + col] = acc[j][r] + swv * bv[col];
    }
  }
}

// Small GEMM for the out-projection: C[m][n] = sum_k A[m][k]*B[n][k] + bias[n].
// 64x64 tile, 4 waves, 2-deep ring -> 512 blocks (full CU coverage); replaces
// the 32-block 256^2 kernel that was latency-bound at ~44 us for 4.3 GFLOP.
__global__ __launch_bounds__(256, 4) void gemm64(
    const unsigned short* __restrict__ A, const unsigned short* __restrict__ Bm,
    const float* __restrict__ bias, float* __restrict__ C,
    int M, int N, int K) {
  __shared__ __align__(16) unsigned short As[2][64 * 32];  // 4 KB x2
  __shared__ __align__(16) unsigned short Bs[2][64 * 32];
  const int nb = N >> 6;
  const int mb = blockIdx.x / nb, nk = blockIdx.x % nb;
  const int t = threadIdx.x;
  const int wv_ = t >> 6, lane = t & 63;
  const int l15 = lane & 15, sr = lane >> 4;
  const int nt = K >> 5;

  const unsigned short* Ab = A + (size_t)mb * 64 * K;
  const unsigned short* Bb = Bm + (size_t)nk * 64 * K;

  const int srow = wv_ * 16 + (lane >> 2);
  const int sg = (lane & 3) ^ ((srow >> 1) & 3);
  const int dL = wv_ * 1024;

  const unsigned short* aG = Ab + (size_t)srow * K + sg * 8;
  const unsigned short* bG = Bb + (size_t)srow * K + sg * 8;

  auto stage = [&](int tt, int q) {
    gload16(aG + tt * 32, (char*)As[q] + dL);
    gload16(bG + tt * 32, (char*)Bs[q] + dL);
  };

  int aOff, bOff[4];
  {
    int r = wv_ * 16 + l15;
    aOff = r * 64 + ((sr ^ ((r >> 1) & 3)) * 16);
  }
  #pragma unroll
  for (int j = 0; j < 4; ++j) {
    int r = j * 16 + l15;
    bOff[j] = r * 64 + ((sr ^ ((r >> 1) & 3)) * 16);
  }

  f32x4 acc[4] = {};
  stage(0, 0);
  for (int tt = 0; tt < nt; ++tt) {
    if (tt + 1 < nt) {
      stage(tt + 1, (tt + 1) & 1);
      asm volatile("s_waitcnt vmcnt(2)" ::: "memory");  // tile tt landed
    } else {
      asm volatile("s_waitcnt vmcnt(0)" ::: "memory");
    }
    __builtin_amdgcn_s_barrier();
    const char* a = (const char*)As[tt & 1];
    const char* bb = (const char*)Bs[tt & 1];
    short8 aF = *(const short8*)(a + aOff);
    short8 bF[4];
    #pragma unroll
    for (int j = 0; j < 4; ++j) bF[j] = *(const short8*)(bb + bOff[j]);
    #pragma unroll
    for (int j = 0; j < 4; ++j)
      acc[j] = __builtin_amdgcn_mfma_f32_16x16x32_bf16(aF, bF[j], acc[j], 0, 0, 0);
    __builtin_amdgcn_s_barrier();
  }

  const int row0 = mb * 64 + wv_ * 16 + sr * 4;
  #pragma unroll
  for (int r = 0; r < 4; ++r) {
    #pragma unroll
    for (int j = 0; j < 4; ++j) {
      int col = nk * 64 + j * 16 + l15;
      C[(size_t)(row0 + r) * N + col] = acc[j][r] + bias[col];
    }
  }
}

// Circular conv along g on (b*512+g, 1024) layout: out[g] = sum_m w_m in[(g+256+m)&511].
__global__ void conv_kernel(const float* __restrict__ field2,
                            unsigned short* __restrict__ fconv2) {
  int i = blockIdx.x * blockDim.x + threadIdx.x;   // 2048*256 float4 units
  int c4 = i & 255;
  int bg = i >> 8;
  int b = bg >> 9, g = bg & 511;
  const float4* f4 = (const float4*)field2;
  const float invZ = 0.86466471f;                  // 1/(sum e^{-2m} + 1e-8)
  float4 s = {0.f, 0.f, 0.f, 0.f};
  #pragma unroll
  for (int m = 0; m <= 20; ++m) {
    float w = expf(-2.0f * (float)m) * invZ;
    float4 v = f4[(size_t)((b << 9) + ((g + 256 + m) & 511)) * 256 + c4];
    s.x += w * v.x; s.y += w * v.y; s.z += w * v.z; s.w += w * v.w;
  }
  ushort4 o;
  o.x = f2bf(s.x); o.y = f2bf(s.y); o.z = f2bf(s.z); o.w = f2bf(s.w);
  *(ushort4*)(fconv2 + (size_t)bg * 1024 + c4 * 4) = o;
}

// Row-expand: out[b,n,:] = small[(b,g(n)),:]  (bias already in small).
__global__ void expand_kernel(const float* __restrict__ small,
                              float* __restrict__ out) {
  const int total = 32768 * 256;                  // rows x (1024/4) float4
  int stride = gridDim.x * blockDim.x;
  for (int i = blockIdx.x * blockDim.x + threadIdx.x; i < total; i += stride) {
    int m = i >> 8;
    int b = m >> 13, n = m & (NN - 1);
    int g = (int)(((float)n / 8191.0f) * 511.0f); // exact ref index math
    ((float4*)out)[i] = ((const float4*)small)[(((b << 9) + g) << 8) + (i & 255)];
  }
}

// ============ 256x256 ring-pipelined MFMA GEMM (k-norm^2 epilogue) ==========
// kn2[row,h] = ||x_row @ Wk_h^T + bk_h||^2 via fused epilogue; each wave's
// 64-col span is one head. 2-phase interleave, ring-4 LDS, counted vmcnt,
// XOR-swizzle (0 bank conflicts, verified R3).
__global__ __launch_bounds__(512, 2) void gemm_knorm(
    const unsigned short* __restrict__ A, const unsigned short* __restrict__ Bm,
    const float* __restrict__ bias, float* __restrict__ Cout,
    int M, int N, int K) {
  __shared__ __align__(16) unsigned short smem[4 * 16384];  // 128 KB

  const int t512 = threadIdx.x;
  const int wv = t512 >> 6, lane = t512 & 63;
  const int wm = wv >> 2, wn = wv & 3;
  const int l15 = lane & 15, sr = lane >> 4;
  const int nt = K >> 5;

  // XCD-aware bijective block swizzle (grid divisible by 8)
  const int nwg = gridDim.x;
  const int lin = blockIdx.x;
  const int swz = (lin & 7) * (nwg >> 3) + (lin >> 3);
  const int gx = N >> 8;
  const int bm = (swz / gx) * 256;
  const int bn = (swz % gx) * 256;

  const int srow0 = wv * 16 + (lane >> 2);
  const int sg = (lane & 3) ^ ((srow0 >> 1) & 3);
  const int aL0 = wv * 1024;
  const int aL1 = 8192 + wv * 1024;

  const unsigned short* aG0 = A + (size_t)(bm + srow0) * K + sg * 8;
  const unsigned short* aG1 = A + (size_t)(bm + srow0 + 128) * K + sg * 8;
  const unsigned short* bG0 = Bm + (size_t)(bn + srow0) * K + sg * 8;
  const unsigned short* bG1 = Bm + (size_t)(bn + srow0 + 128) * K + sg * 8;

  auto stageA = [&](int t, int q) {
    char* base = (char*)smem + q * 32768;
    gload16(aG0 + (size_t)t * 32, base + aL0);
    gload16(aG1 + (size_t)t * 32, base + aL1);
  };
  auto stageB = [&](int t, int q) {
    char* base = (char*)smem + q * 32768;
    gload16(bG0 + (size_t)t * 32, base + 16384 + aL0);
    gload16(bG1 + (size_t)t * 32, base + 16384 + aL1);
  };

  int aOffB[8], bOffB[4];
  #pragma unroll
  for (int i = 0; i < 8; ++i) {
    int r = wm * 128 + i * 16 + l15;
    aOffB[i] = r * 64 + ((sr ^ ((r >> 1) & 3)) * 16);
  }
  #pragma unroll
  for (int j = 0; j < 4; ++j) {
    int r = wn * 64 + j * 16 + l15;
    bOffB[j] = r * 64 + ((sr ^ ((r >> 1) & 3)) * 16);
  }

  f32x4 acc[8][4] = {};

  stageA(0, 0); stageB(0, 0);
  stageA(1, 1); stageB(1, 1);
  stageA(2, 2); stageB(2, 2);
  asm volatile("s_waitcnt vmcnt(8)" ::: "memory");
  __builtin_amdgcn_s_barrier();

  for (int t = 0; t < nt; ++t) {
    const char* base = (const char*)smem + (t & 3) * 32768;
    short8 aF[8], bF[4];

    if (t + 3 < nt) stageA(t + 3, (t + 3) & 3);
    #pragma unroll
    for (int i = 0; i < 4; ++i) aF[i] = *(const short8*)(base + aOffB[i]);
    #pragma unroll
    for (int j = 0; j < 4; ++j) bF[j] = *(const short8*)(base + 16384 + bOffB[j]);
    __builtin_amdgcn_s_barrier();
    __builtin_amdgcn_s_setprio(1);
    #pragma unroll
    for (int i = 0; i < 4; ++i)
      #pragma unroll
      for (int j = 0; j < 4; ++j)
        acc[i][j] = __builtin_amdgcn_mfma_f32_16x16x32_bf16(aF[i], bF[j], acc[i][j], 0, 0, 0);
    __builtin_amdgcn_s_setprio(0);
    __builtin_amdgcn_s_barrier();

    if (t + 3 < nt) stageB(t + 3, (t + 3) & 3);
    #pragma unroll
    for (int i = 4; i < 8; ++i) aF[i] = *(const short8*)(base + aOffB[i]);
    {
      int rem = nt - 1 - t;
      if (rem >= 3)      asm volatile("s_waitcnt vmcnt(8)" ::: "memory");
      else if (rem == 2) asm volatile("s_waitcnt vmcnt(4)" ::: "memory");
      else               asm volatile("s_waitcnt vmcnt(0)" ::: "memory");
    }
    __builtin_amdgcn_s_barrier();
    __builtin_amdgcn_s_setprio(1);
    #pragma unroll
    for (int i = 4; i < 8; ++i)
      #pragma unroll
      for (int j = 0; j < 4; ++j)
        acc[i][j] = __builtin_amdgcn_mfma_f32_16x16x32_bf16(aF[i], bF[j], acc[i][j], 0, 0, 0);
    __builtin_amdgcn_s_setprio(0);
    __builtin_amdgcn_s_barrier();
  }

  // Fused k-norm^2 epilogue: this wave's cols bn+wn*64..+64 = head (bn>>6)+wn.
  const int hcol = (bn >> 6) + wn;
  float kb[4];
  #pragma unroll
  for (int j = 0; j < 4; ++j) kb[j] = bias[bn + wn * 64 + j * 16 + l15];
  #pragma unroll
  for (int i = 0; i < 8; ++i) {
    #pragma unroll
    for (int r = 0; r < 4; ++r) {
      float s = 0.0f;
      #pragma unroll
      for (int j = 0; j < 4; ++j) {
        float val = acc[i][j][r] + kb[j];
        s += val * val;
      }
      s += __shfl_xor(s, 1, 64);
      s += __shfl_xor(s, 2, 64);
      s += __shfl_xor(s, 4, 64);
      s += __shfl_xor(s, 8, 64);
      if (l15 == 0) {
        int row = bm + wm * 128 + i * 16 + sr * 4 + r;
        Cout[(size_t)row * 16 + hcol] = s;
      }
    }
  }
}

extern "C" void kernel_launch(void* const* d_in, const int* in_sizes, int n_in,
                              void* d_out, int out_size, void* d_ws, size_t ws_size,
                              hipStream_t stream) {
  const float* x    = (const float*)d_in[0];   // (4,8192,1024)
  const float* Wqkv = (const float*)d_in[1];   // (3072,1024)
  const float* bqkv = (const float*)d_in[2];   // (3072,)
  const float* Wout = (const float*)d_in[3];   // (1024,1024)
  const float* bout = (const float*)d_in[4];   // (1024,)
  float* out = (float*)d_out;                  // (4,8192,1024) f32

  const size_t M = (size_t)BB * NN;            // 32768

  // Workspace layout
  char* ws = (char*)d_ws;
  size_t off = 0;
  unsigned short* xb    = (unsigned short*)(ws + off); off += M * DD * 2;            // 64 MB
  unsigned short* wkb   = (unsigned short*)(ws + off); off += (size_t)DD * DD * 2;   // 2 MB
  unsigned short* wvb   = (unsigned short*)(ws + off); off += (size_t)DD * DD * 2;   // 2 MB
  unsigned short* woutb = (unsigned short*)(ws + off); off += (size_t)DD * DD * 2;   // 2 MB
  float*          kn2   = (float*)(ws + off);          off += M * HH * 4;            // 2 MB
  unsigned short* xwb   = (unsigned short*)(ws + off); off += (size_t)HH*BB*GG*DD*2; // 64 MB
  float*          field2= (float*)(ws + off);          off += (size_t)BB*GG*DD*4;    // 8 MB
  unsigned short* fconv2= (unsigned short*)(ws + off); off += (size_t)BB*GG*DD*2;    // 4 MB
  float*          sw    = (float*)(ws + off);          off += (size_t)BB*GG*HH*4;    // 128 KB
  float* small = (float*)xb;   // 8 MB, aliases xb (dead after xw_kernel)

  // 1. bf16 conversions: x (big), then Wk/Wv/Wout merged
  cvt_kernel<<<8192, 256, 0, stream>>>(x, xb, (int)(M * DD / 4));
  cvtw_kernel<<<3072, 256, 0, stream>>>(Wqkv, Wout, wkb, wvb, woutb);

  // 2. kn2[n,h] = ||x_n @ Wk_h^T + bk_h||^2  (fused epilogue; no k materialized)
  gemm_knorm<<<(DD / 256) * (M / 256), 512, 0, stream>>>(
      xb, wkb, bqkv + DD, kn2, (int)M, DD, DD);

  // 3. xw[h,(b,g),:] = sum_{n in g} sqrt(kn2) * x[n,:]; sw = sum of weights
  xw_kernel<<<BB * GG, 256, 0, stream>>>(xb, kn2, xwb, sw);

  // 4. field2[(b,g), h*64+d] = xw_h @ Wv_h^T + sw*bv
  field_gemm<<<HH * 32, 256, 0, stream>>>(xwb, wvb, sw, bqkv + 2 * DD, field2);

  // 5. circular conv along g -> bf16 (b*512+g, 1024)
  conv_kernel<<<BB * GG, 256, 0, stream>>>(field2, fconv2);

  // 6. small = fconv2 @ Wout^T + bout  (2048 x 1024 f32) — 64x64 tiles, 512 blocks
  gemm64<<<(BB * GG / 64) * (DD / 64), 256, 0, stream>>>(
      fconv2, woutb, bout, small, BB * GG, DD, DD);

  // 7. out[b,n,:] = small[(b,g(n)),:]
  expand_kernel<<<4096, 256, 0, stream>>>(small, out);
}

// Round 8
// 229.072 us; speedup vs baseline: 1.7598x; 1.0102x over previous
//
#include <hip/hip_runtime.h>

// Problem constants (B=4, N=8192, D=1024, H=16, hd=64, G=512)
#define BB 4
#define NN 8192
#define DD 1024
#define HH 16
#define HD 64
#define GG 512

typedef short short8 __attribute__((ext_vector_type(8)));
typedef float f32x4 __attribute__((ext_vector_type(4)));

__device__ __forceinline__ unsigned short f2bf(float f) {
  union { float f; unsigned int u; } v; v.f = f;
  unsigned int r = v.u + 0x7FFFu + ((v.u >> 16) & 1u);
  return (unsigned short)(r >> 16);
}
__device__ __forceinline__ float bf2f(unsigned short b) {
  union { unsigned int u; float f; } v; v.u = ((unsigned int)b) << 16;
  return v.f;
}

// Async global->LDS 16B copy: LDS dest = wave-uniform base + lane*16 (m104);
// global src is per-lane (m173).
__device__ __forceinline__ void gload16(const void* g, void* l) {
  __builtin_amdgcn_global_load_lds((const __attribute__((address_space(1))) void*)g,
                                   (__attribute__((address_space(3))) void*)l,
                                   16, 0, 0);
}

// Merged f32->bf16 convert: x (8,388,608 float4) then Wk/Wv/Wout (262,144 each).
__global__ void cvt_all(const float* __restrict__ x, const float* __restrict__ Wqkv,
                        const float* __restrict__ Wout,
                        unsigned short* __restrict__ xb, unsigned short* __restrict__ wkb,
                        unsigned short* __restrict__ wvb, unsigned short* __restrict__ woutb) {
  const int total = 8388608 + 3 * 262144;
  int stride = gridDim.x * blockDim.x;
  for (int j = blockIdx.x * blockDim.x + threadIdx.x; j < total; j += stride) {
    const float4* s; ushort4* d; int r;
    if (j < 8388608) { s = (const float4*)x; d = (ushort4*)xb; r = j; }
    else {
      int q = j - 8388608; int seg = q >> 18; r = q & 262143;
      if (seg == 0)      { s = (const float4*)(Wqkv + 1048576); d = (ushort4*)wkb; }
      else if (seg == 1) { s = (const float4*)(Wqkv + 2097152); d = (ushort4*)wvb; }
      else               { s = (const float4*)Wout;             d = (ushort4*)woutb; }
    }
    float4 f = s[r];
    ushort4 u;
    u.x = f2bf(f.x); u.y = f2bf(f.y); u.z = f2bf(f.z); u.w = f2bf(f.w);
    d[r] = u;
  }
}

// xw: per (b,g) bucket, xw[h,:] = sum_{n in g} w[n,h] * x[n,:]; sw[h] = sum w.
// kw already holds w = ||k|| (sqrt fused into gemm_knorm epilogue).
// Window of 20 n covers any bucket (width ~16.03); membership-flagged rows only
// (skipping non-members is bit-identical: their w was exactly 0).
__global__ __launch_bounds__(256) void xw_kernel(
    const unsigned short* __restrict__ xb, const float* __restrict__ kw,
    unsigned short* __restrict__ xwb, float* __restrict__ sw) {
  __shared__ float w_l[20][16];
  __shared__ int mflag[20];
  const int bg = blockIdx.x;             // b*512+g
  const int b = bg >> 9, g = bg & 511;
  const int t = threadIdx.x;
  int lo = (g * (NN - 1)) / (GG - 1) - 2;
  if (lo < 0) lo = 0;
  if (t < 20) {
    int n = lo + t;
    // EXACT ref bucket math: trunc((n/8191)*511)
    mflag[t] = (n < NN) && ((int)(((float)n / 8191.0f) * 511.0f) == g);
  }
  for (int u = t; u < 320; u += 256) {
    int ln = u >> 4, h = u & 15;
    int n = lo + ln;
    float w = 0.0f;
    if (n < NN && (int)(((float)n / 8191.0f) * 511.0f) == g)
      w = kw[((size_t)(b * NN + n)) * 16 + h];
    w_l[ln][h] = w;
  }
  __syncthreads();
  if (t < 16) {
    float s = 0.0f;
    #pragma unroll
    for (int ln = 0; ln < 20; ++ln) s += w_l[ln][t];
    sw[bg * 16 + t] = s;
  }
  float acc[16][4] = {};
  const int c0 = t * 4;
  for (int ln = 0; ln < 20; ++ln) {
    if (!mflag[ln]) continue;            // wave-uniform branch
    int n = lo + ln;
    ushort4 xv = *(const ushort4*)(xb + ((size_t)(b * NN + n)) * 1024 + c0);
    float x0 = bf2f(xv.x), x1 = bf2f(xv.y), x2 = bf2f(xv.z), x3 = bf2f(xv.w);
    #pragma unroll
    for (int h = 0; h < 16; ++h) {
      float w = w_l[ln][h];
      acc[h][0] += w * x0; acc[h][1] += w * x1;
      acc[h][2] += w * x2; acc[h][3] += w * x3;
    }
  }
  #pragma unroll
  for (int h = 0; h < 16; ++h) {
    ushort4 o;
    o.x = f2bf(acc[h][0]); o.y = f2bf(acc[h][1]);
    o.z = f2bf(acc[h][2]); o.w = f2bf(acc[h][3]);
    *(ushort4*)(xwb + ((size_t)h * 2048 + bg) * 1024 + c0) = o;
  }
}

// field GEMM: per h, field2[(b,g), h*64+d] = xw_h[(b,g),:] . Wv[h*64+d,:] + sw*bv.
// M-tile 64, N=64 (one head), K=1024. 4 waves, 2-deep ring, counted vmcnt.
__global__ __launch_bounds__(256, 2) void field_gemm(
    const unsigned short* __restrict__ xwb, const unsigned short* __restrict__ wvb,
    const float* __restrict__ sw, const float* __restrict__ bv,
    float* __restrict__ field2) {
  __shared__ __align__(16) unsigned short As[2][64 * 32];  // 4 KB x2
  __shared__ __align__(16) unsigned short Bs[2][64 * 32];  // 4 KB x2
  const int h = blockIdx.x >> 5;           // 16 h
  const int mb = blockIdx.x & 31;          // 32 m-blocks of 64
  const int t = threadIdx.x;
  const int wv_ = t >> 6, lane = t & 63;
  const int l15 = lane & 15, sr = lane >> 4;

  const unsigned short* Ah = xwb + (size_t)h * 2048 * 1024 + (size_t)mb * 64 * 1024;
  const unsigned short* Bh = wvb + (size_t)h * 64 * 1024;

  const int srow = wv_ * 16 + (lane >> 2);          // 0..63
  const int sg = (lane & 3) ^ ((srow >> 1) & 3);    // swizzled k-segment
  const int dL = wv_ * 1024;                        // wave-uniform LDS bytes

  const unsigned short* aG = Ah + (size_t)srow * 1024 + sg * 8;
  const unsigned short* bG = Bh + (size_t)srow * 1024 + sg * 8;

  auto stage = [&](int tt, int q) {
    gload16(aG + tt * 32, (char*)As[q] + dL);
    gload16(bG + tt * 32, (char*)Bs[q] + dL);
  };

  int aOff, bOff[4];
  {
    int r = wv_ * 16 + l15;
    aOff = r * 64 + ((sr ^ ((r >> 1) & 3)) * 16);
  }
  #pragma unroll
  for (int j = 0; j < 4; ++j) {
    int r = j * 16 + l15;
    bOff[j] = r * 64 + ((sr ^ ((r >> 1) & 3)) * 16);
  }

  f32x4 acc[4] = {};
  stage(0, 0);
  for (int tt = 0; tt < 32; ++tt) {
    if (tt + 1 < 32) {
      stage(tt + 1, (tt + 1) & 1);
      asm volatile("s_waitcnt vmcnt(2)" ::: "memory");  // tile tt landed
    } else {
      asm volatile("s_waitcnt vmcnt(0)" ::: "memory");
    }
    __builtin_amdgcn_s_barrier();
    const char* a = (const char*)As[tt & 1];
    const char* bb = (const char*)Bs[tt & 1];
    short8 aF = *(const short8*)(a + aOff);
    short8 bF[4];
    #pragma unroll
    for (int j = 0; j < 4; ++j) bF[j] = *(const short8*)(bb + bOff[j]);
    #pragma unroll
    for (int j = 0; j < 4; ++j)
      acc[j] = __builtin_amdgcn_mfma_f32_16x16x32_bf16(aF, bF[j], acc[j], 0, 0, 0);
    __builtin_amdgcn_s_barrier();
  }

  const int row0 = mb * 64 + wv_ * 16 + sr * 4;
  #pragma unroll
  for (int r = 0; r < 4; ++r) {
    float swv = sw[(row0 + r) * 16 + h];
    #pragma unroll
    for (int j = 0; j < 4; ++j) {
      int col = h * 64 + j * 16 + l15;
      field2[(size_t)(row0 + r) * 1024 + col] = acc[j][r] + swv * bv[col];
    }
  }
}

// Small GEMM for the out-projection: C[m][n] = sum_k A[m][k]*B[n][k] + bias[n].
// 64x64 tile, 4 waves, 2-deep ring -> 512 blocks (full CU coverage).
__global__ __launch_bounds__(256, 4) void gemm64(
    const unsigned short* __restrict__ A, const unsigned short* __restrict__ Bm,
    const float* __restrict__ bias, float* __restrict__ C,
    int M, int N, int K) {
  __shared__ __align__(16) unsigned short As[2][64 * 32];  // 4 KB x2
  __shared__ __align__(16) unsigned short Bs[2][64 * 32];
  const int nb = N >> 6;
  const int mb = blockIdx.x / nb, nk = blockIdx.x % nb;
  const int t = threadIdx.x;
  const int wv_ = t >> 6, lane = t & 63;
  const int l15 = lane & 15, sr = lane >> 4;
  const int nt = K >> 5;

  const unsigned short* Ab = A + (size_t)mb * 64 * K;
  const unsigned short* Bb = Bm + (size_t)nk * 64 * K;

  const int srow = wv_ * 16 + (lane >> 2);
  const int sg = (lane & 3) ^ ((srow >> 1) & 3);
  const int dL = wv_ * 1024;

  const unsigned short* aG = Ab + (size_t)srow * K + sg * 8;
  const unsigned short* bG = Bb + (size_t)srow * K + sg * 8;

  auto stage = [&](int tt, int q) {
    gload16(aG + tt * 32, (char*)As[q] + dL);
    gload16(bG + tt * 32, (char*)Bs[q] + dL);
  };

  int aOff, bOff[4];
  {
    int r = wv_ * 16 + l15;
    aOff = r * 64 + ((sr ^ ((r >> 1) & 3)) * 16);
  }
  #pragma unroll
  for (int j = 0; j < 4; ++j) {
    int r = j * 16 + l15;
    bOff[j] = r * 64 + ((sr ^ ((r >> 1) & 3)) * 16);
  }

  f32x4 acc[4] = {};
  stage(0, 0);
  for (int tt = 0; tt < nt; ++tt) {
    if (tt + 1 < nt) {
      stage(tt + 1, (tt + 1) & 1);
      asm volatile("s_waitcnt vmcnt(2)" ::: "memory");  // tile tt landed
    } else {
      asm volatile("s_waitcnt vmcnt(0)" ::: "memory");
    }
    __builtin_amdgcn_s_barrier();
    const char* a = (const char*)As[tt & 1];
    const char* bb = (const char*)Bs[tt & 1];
    short8 aF = *(const short8*)(a + aOff);
    short8 bF[4];
    #pragma unroll
    for (int j = 0; j < 4; ++j) bF[j] = *(const short8*)(bb + bOff[j]);
    #pragma unroll
    for (int j = 0; j < 4; ++j)
      acc[j] = __builtin_amdgcn_mfma_f32_16x16x32_bf16(aF, bF[j], acc[j], 0, 0, 0);
    __builtin_amdgcn_s_barrier();
  }

  const int row0 = mb * 64 + wv_ * 16 + sr * 4;
  #pragma unroll
  for (int r = 0; r < 4; ++r) {
    #pragma unroll
    for (int j = 0; j < 4; ++j) {
      int col = nk * 64 + j * 16 + l15;
      C[(size_t)(row0 + r) * N + col] = acc[j][r] + bias[col];
    }
  }
}

// Circular conv along g on (b*512+g, 1024) layout: out[g] = sum_m w_m in[(g+256+m)&511],
// w_m = invZ * e^{-2m} computed iteratively (no expf).
__global__ void conv_kernel(const float* __restrict__ field2,
                            unsigned short* __restrict__ fconv2) {
  int i = blockIdx.x * blockDim.x + threadIdx.x;   // 2048*256 float4 units
  int c4 = i & 255;
  int bg = i >> 8;
  int b = bg >> 9, g = bg & 511;
  const float4* f4 = (const float4*)field2;
  float w = 0.86466471f;                           // invZ = 1/(sum e^{-2m} + 1e-8)
  const float dec = 0.13533528f;                   // e^{-2}
  float4 s = {0.f, 0.f, 0.f, 0.f};
  #pragma unroll
  for (int m = 0; m <= 20; ++m) {
    float4 v = f4[(size_t)((b << 9) + ((g + 256 + m) & 511)) * 256 + c4];
    s.x += w * v.x; s.y += w * v.y; s.z += w * v.z; s.w += w * v.w;
    w *= dec;
  }
  ushort4 o;
  o.x = f2bf(s.x); o.y = f2bf(s.y); o.z = f2bf(s.z); o.w = f2bf(s.w);
  *(ushort4*)(fconv2 + (size_t)bg * 1024 + c4 * 4) = o;
}

// Row-expand: out[b,n,:] = small[(b,g(n)),:]  (bias already in small).
__global__ void expand_kernel(const float* __restrict__ small,
                              float* __restrict__ out) {
  const int total = 32768 * 256;                  // rows x (1024/4) float4
  int stride = gridDim.x * blockDim.x;
  for (int i = blockIdx.x * blockDim.x + threadIdx.x; i < total; i += stride) {
    int m = i >> 8;
    int b = m >> 13, n = m & (NN - 1);
    int g = (int)(((float)n / 8191.0f) * 511.0f); // exact ref index math
    ((float4*)out)[i] = ((const float4*)small)[(((b << 9) + g) << 8) + (i & 255)];
  }
}

// ============ 256x256 ring-pipelined MFMA GEMM (k-norm epilogue) ============
// kw[row,h] = ||x_row @ Wk_h^T + bk_h|| via fused epilogue (sqrt included);
// each wave's 64-col span is one head. 2-phase interleave, ring-4 LDS,
// counted vmcnt, XOR-swizzle (0 bank conflicts, verified R3).
__global__ __launch_bounds__(512, 2) void gemm_knorm(
    const unsigned short* __restrict__ A, const unsigned short* __restrict__ Bm,
    const float* __restrict__ bias, float* __restrict__ Cout,
    int M, int N, int K) {
  __shared__ __align__(16) unsigned short smem[4 * 16384];  // 128 KB

  const int t512 = threadIdx.x;
  const int wv = t512 >> 6, lane = t512 & 63;
  const int wm = wv >> 2, wn = wv & 3;
  const int l15 = lane & 15, sr = lane >> 4;
  const int nt = K >> 5;

  // XCD-aware bijective block swizzle (grid divisible by 8)
  const int nwg = gridDim.x;
  const int lin = blockIdx.x;
  const int swz = (lin & 7) * (nwg >> 3) + (lin >> 3);
  const int gx = N >> 8;
  const int bm = (swz / gx) * 256;
  const int bn = (swz % gx) * 256;

  const int srow0 = wv * 16 + (lane >> 2);
  const int sg = (lane & 3) ^ ((srow0 >> 1) & 3);
  const int aL0 = wv * 1024;
  const int aL1 = 8192 + wv * 1024;

  const unsigned short* aG0 = A + (size_t)(bm + srow0) * K + sg * 8;
  const unsigned short* aG1 = A + (size_t)(bm + srow0 + 128) * K + sg * 8;
  const unsigned short* bG0 = Bm + (size_t)(bn + srow0) * K + sg * 8;
  const unsigned short* bG1 = Bm + (size_t)(bn + srow0 + 128) * K + sg * 8;

  auto stageA = [&](int t, int q) {
    char* base = (char*)smem + q * 32768;
    gload16(aG0 + (size_t)t * 32, base + aL0);
    gload16(aG1 + (size_t)t * 32, base + aL1);
  };
  auto stageB = [&](int t, int q) {
    char* base = (char*)smem + q * 32768;
    gload16(bG0 + (size_t)t * 32, base + 16384 + aL0);
    gload16(bG1 + (size_t)t * 32, base + 16384 + aL1);
  };

  int aOffB[8], bOffB[4];
  #pragma unroll
  for (int i = 0; i < 8; ++i) {
    int r = wm * 128 + i * 16 + l15;
    aOffB[i] = r * 64 + ((sr ^ ((r >> 1) & 3)) * 16);
  }
  #pragma unroll
  for (int j = 0; j < 4; ++j) {
    int r = wn * 64 + j * 16 + l15;
    bOffB[j] = r * 64 + ((sr ^ ((r >> 1) & 3)) * 16);
  }

  f32x4 acc[8][4] = {};

  stageA(0, 0); stageB(0, 0);
  stageA(1, 1); stageB(1, 1);
  stageA(2, 2); stageB(2, 2);
  asm volatile("s_waitcnt vmcnt(8)" ::: "memory");
  __builtin_amdgcn_s_barrier();

  for (int t = 0; t < nt; ++t) {
    const char* base = (const char*)smem + (t & 3) * 32768;
    short8 aF[8], bF[4];

    if (t + 3 < nt) stageA(t + 3, (t + 3) & 3);
    #pragma unroll
    for (int i = 0; i < 4; ++i) aF[i] = *(const short8*)(base + aOffB[i]);
    #pragma unroll
    for (int j = 0; j < 4; ++j) bF[j] = *(const short8*)(base + 16384 + bOffB[j]);
    __builtin_amdgcn_s_barrier();
    __builtin_amdgcn_s_setprio(1);
    #pragma unroll
    for (int i = 0; i < 4; ++i)
      #pragma unroll
      for (int j = 0; j < 4; ++j)
        acc[i][j] = __builtin_amdgcn_mfma_f32_16x16x32_bf16(aF[i], bF[j], acc[i][j], 0, 0, 0);
    __builtin_amdgcn_s_setprio(0);
    __builtin_amdgcn_s_barrier();

    if (t + 3 < nt) stageB(t + 3, (t + 3) & 3);
    #pragma unroll
    for (int i = 4; i < 8; ++i) aF[i] = *(const short8*)(base + aOffB[i]);
    {
      int rem = nt - 1 - t;
      if (rem >= 3)      asm volatile("s_waitcnt vmcnt(8)" ::: "memory");
      else if (rem == 2) asm volatile("s_waitcnt vmcnt(4)" ::: "memory");
      else               asm volatile("s_waitcnt vmcnt(0)" ::: "memory");
    }
    __builtin_amdgcn_s_barrier();
    __builtin_amdgcn_s_setprio(1);
    #pragma unroll
    for (int i = 4; i < 8; ++i)
      #pragma unroll
      for (int j = 0; j < 4; ++j)
        acc[i][j] = __builtin_amdgcn_mfma_f32_16x16x32_bf16(aF[i], bF[j], acc[i][j], 0, 0, 0);
    __builtin_amdgcn_s_setprio(0);
    __builtin_amdgcn_s_barrier();
  }

  // Fused k-norm epilogue: this wave's cols bn+wn*64..+64 = head (bn>>6)+wn.
  const int hcol = (bn >> 6) + wn;
  float kb[4];
  #pragma unroll
  for (int j = 0; j < 4; ++j) kb[j] = bias[bn + wn * 64 + j * 16 + l15];
  #pragma unroll
  for (int i = 0; i < 8; ++i) {
    #pragma unroll
    for (int r = 0; r < 4; ++r) {
      float s = 0.0f;
      #pragma unroll
      for (int j = 0; j < 4; ++j) {
        float val = acc[i][j][r] + kb[j];
        s += val * val;
      }
      s += __shfl_xor(s, 1, 64);
      s += __shfl_xor(s, 2, 64);
      s += __shfl_xor(s, 4, 64);
      s += __shfl_xor(s, 8, 64);
      if (l15 == 0) {
        int row = bm + wm * 128 + i * 16 + sr * 4 + r;
        Cout[(size_t)row * 16 + hcol] = sqrtf(s);
      }
    }
  }
}

extern "C" void kernel_launch(void* const* d_in, const int* in_sizes, int n_in,
                              void* d_out, int out_size, void* d_ws, size_t ws_size,
                              hipStream_t stream) {
  const float* x    = (const float*)d_in[0];   // (4,8192,1024)
  const float* Wqkv = (const float*)d_in[1];   // (3072,1024)
  const float* bqkv = (const float*)d_in[2];   // (3072,)
  const float* Wout = (const float*)d_in[3];   // (1024,1024)
  const float* bout = (const float*)d_in[4];   // (1024,)
  float* out = (float*)d_out;                  // (4,8192,1024) f32

  const size_t M = (size_t)BB * NN;            // 32768

  // Workspace layout
  char* ws = (char*)d_ws;
  size_t off = 0;
  unsigned short* xb    = (unsigned short*)(ws + off); off += M * DD * 2;            // 64 MB
  unsigned short* wkb   = (unsigned short*)(ws + off); off += (size_t)DD * DD * 2;   // 2 MB
  unsigned short* wvb   = (unsigned short*)(ws + off); off += (size_t)DD * DD * 2;   // 2 MB
  unsigned short* woutb = (unsigned short*)(ws + off); off += (size_t)DD * DD * 2;   // 2 MB
  float*          kw    = (float*)(ws + off);          off += M * HH * 4;            // 2 MB
  unsigned short* xwb   = (unsigned short*)(ws + off); off += (size_t)HH*BB*GG*DD*2; // 64 MB
  float*          field2= (float*)(ws + off);          off += (size_t)BB*GG*DD*4;    // 8 MB
  unsigned short* fconv2= (unsigned short*)(ws + off); off += (size_t)BB*GG*DD*2;    // 4 MB
  float*          sw    = (float*)(ws + off);          off += (size_t)BB*GG*HH*4;    // 128 KB
  float* small = (float*)xb;   // 8 MB, aliases xb (dead after xw_kernel)

  // 1. bf16 conversions: x + Wk/Wv/Wout in one kernel
  cvt_all<<<8960, 256, 0, stream>>>(x, Wqkv, Wout, xb, wkb, wvb, woutb);

  // 2. kw[n,h] = ||x_n @ Wk_h^T + bk_h||  (fused epilogue; no k materialized)
  gemm_knorm<<<(DD / 256) * (M / 256), 512, 0, stream>>>(
      xb, wkb, bqkv + DD, kw, (int)M, DD, DD);

  // 3. xw[h,(b,g),:] = sum_{n in g} w * x[n,:]; sw = sum of weights
  xw_kernel<<<BB * GG, 256, 0, stream>>>(xb, kw, xwb, sw);

  // 4. field2[(b,g), h*64+d] = xw_h @ Wv_h^T + sw*bv
  field_gemm<<<HH * 32, 256, 0, stream>>>(xwb, wvb, sw, bqkv + 2 * DD, field2);

  // 5. circular conv along g -> bf16 (b*512+g, 1024)
  conv_kernel<<<BB * GG, 256, 0, stream>>>(field2, fconv2);

  // 6. small = fconv2 @ Wout^T + bout  (2048 x 1024 f32) — 64x64 tiles, 512 blocks
  gemm64<<<(BB * GG / 64) * (DD / 64), 256, 0, stream>>>(
      fconv2, woutb, bout, small, BB * GG, DD, DD);

  // 7. out[b,n,:] = small[(b,g(n)),:]
  expand_kernel<<<4096, 256, 0, stream>>>(small, out);
}